// Round 1
// 424.939 us; speedup vs baseline: 1.1272x; 1.1272x over previous
//
#include <hip/hip_runtime.h>
#include <stdint.h>

typedef unsigned short ushort_t;
typedef float f32x4 __attribute__((ext_vector_type(4)));
typedef short s16x8 __attribute__((ext_vector_type(8)));

#define B_  32
#define D_  4096
#define H1_ 512
#define H2_ 256
#define U_  64

#define KS_   16        // K-splits for forward GEMM
#define KCH_  256       // K per block (4096/16)
#define NT_   128       // N tile per block
#define APAD  264       // A_lds row stride (u16): 256 + 8 (16B aligned)
#define WPAD  72        // Wt_lds row stride (u16): 64 + 8 (16B aligned)

__device__ __forceinline__ float bf2f(ushort_t u) {
    return __uint_as_float(((uint32_t)u) << 16);
}
__device__ __forceinline__ ushort_t f2bfu(float f) {  // RNE float->bf16 bits
    uint32_t x = __float_as_uint(f);
    return (ushort_t)((x + 0x7fffu + ((x >> 16) & 1u)) >> 16);
}
__device__ __forceinline__ uint32_t pk2bf(float a, float b) {
    return ((uint32_t)f2bfu(a)) | (((uint32_t)f2bfu(b)) << 16);
}

// ---------------------------------------------------------------------------
// K1: forward GEMMs via MFMA 16x16x32 bf16.
// C[b][n] = sum_k A[b][k] * W[k][n], A=[32 x 4096] fp32, W=[4096 x 4096] fp32.
// grid 1024: [gemm(2)][nblk(32)][kchunk(16)].  Block: 256 thr = 4 waves.
// Wave w owns n-subtile [w*32, w*32+32): 2 m-tiles x 2 n-tiles of 16x16.
// W tile staged fp32->bf16 TRANSPOSED into LDS (Wt[n][k]) so b-frags are
// contiguous ds_read_b128.
// K-split partials: when ns==16 each chunk writes its OWN Psum slice with
// plain stores (no atomics); ns<16 falls back to atomicAdd into chunk%ns.
// ---------------------------------------------------------------------------
__global__ __launch_bounds__(256, 4) void k_gemm_mfma(
    const float* __restrict__ stim, const float* __restrict__ prev,
    const float* __restrict__ Wheb, const float* __restrict__ Wrec,
    float* __restrict__ Psum, int ns)
{
    __shared__ ushort_t Al[32 * APAD];     // 16.5 KB
    __shared__ ushort_t Wt[NT_ * WPAD];    // 18.0 KB

    int bx = blockIdx.x;
    int gemm  = bx >> 9;
    int rem   = bx & 511;
    int nblk  = rem >> 4;
    int chunk = rem & 15;
    const float* A = gemm ? prev : stim;
    const float* W = gemm ? Wrec : Wheb;
    int k0c = chunk * KCH_;
    int n0  = nblk * NT_;
    int tid = threadIdx.x, lane = tid & 63, wave = tid >> 6;
    int col = lane & 15, quad = lane >> 4;

    // ---- stage A [32][256] fp32 -> bf16 LDS (once per block)
#pragma unroll
    for (int p = 0; p < 16; p++) {
        int idx = p * 256 + tid;           // over [32][128] float2
        int b   = idx >> 7;
        int kk  = (idx & 127) * 2;
        float2 v = *(const float2*)(A + (size_t)b * D_ + k0c + kk);
        *(uint32_t*)&Al[b * APAD + kk] = pk2bf(v.x, v.y);
    }

    f32x4 acc[2][2];
#pragma unroll
    for (int mt = 0; mt < 2; mt++)
#pragma unroll
        for (int nt = 0; nt < 2; nt++)
            acc[mt][nt] = (f32x4){0.f, 0.f, 0.f, 0.f};

    int wcol = tid & 127;                  // column within N tile
    int kh   = (tid >> 7) * 32;            // k offset within kstep (0 or 32)

    // ---- K loop: 4 ksteps of 64
    for (int ks = 0; ks < 4; ks++) {
        __syncthreads();                   // protect Wt before overwrite
        // stage W kstep: 2 threads per column, 32 k each (16 bf16 pairs)
        const float* Wc = W + (size_t)(k0c + ks * 64 + kh) * D_ + n0 + wcol;
        uint32_t* dst = (uint32_t*)&Wt[wcol * WPAD] + (kh >> 1);
#pragma unroll
        for (int i = 0; i < 16; i++) {
            float a = Wc[(size_t)(2 * i) * D_];
            float b = Wc[(size_t)(2 * i + 1) * D_];
            dst[i] = pk2bf(a, b);
        }
        __syncthreads();

#pragma unroll
        for (int kq = 0; kq < 2; kq++) {
            int kb = ks * 64 + kq * 32 + quad * 8;   // k in A_lds chunk
            int kw = kq * 32 + quad * 8;             // k in Wt row
            s16x8 af[2], bf[2];
            af[0] = *(const s16x8*)&Al[col * APAD + kb];
            af[1] = *(const s16x8*)&Al[(col + 16) * APAD + kb];
#pragma unroll
            for (int nt = 0; nt < 2; nt++)
                bf[nt] = *(const s16x8*)&Wt[(wave * 32 + nt * 16 + col) * WPAD + kw];
#pragma unroll
            for (int mt = 0; mt < 2; mt++)
#pragma unroll
                for (int nt = 0; nt < 2; nt++)
                    acc[mt][nt] = __builtin_amdgcn_mfma_f32_16x16x32_bf16(
                        af[mt], bf[nt], acc[mt][nt], 0, 0, 0);
        }
    }

    // ---- epilogue: write K-split partials to this chunk's slice
    int slice = chunk % ns;                // ns==16 -> slice==chunk (exclusive)
    float* P = Psum + ((size_t)slice * 2 + gemm) * 32 * D_;
    if (ns == 16) {
#pragma unroll
        for (int mt = 0; mt < 2; mt++)
#pragma unroll
            for (int nt = 0; nt < 2; nt++)
#pragma unroll
                for (int r = 0; r < 4; r++) {
                    int b = mt * 16 + quad * 4 + r;
                    int n = n0 + wave * 32 + nt * 16 + col;
                    P[(size_t)b * D_ + n] = acc[mt][nt][r];
                }
    } else {
#pragma unroll
        for (int mt = 0; mt < 2; mt++)
#pragma unroll
            for (int nt = 0; nt < 2; nt++)
#pragma unroll
                for (int r = 0; r < 4; r++) {
                    int b = mt * 16 + quad * 4 + r;
                    int n = n0 + wave * 32 + nt * 16 + col;
                    atomicAdd(&P[(size_t)b * D_ + n], acc[mt][nt][r]);
                }
    }
}

// ---------------------------------------------------------------------------
// K2: sum slices + relu -> P_relu (fp32) + build bf16 transposed copies:
//   Tbuf sections of 4096*32 u16: [0]=ST (stim^T), [1]=PT (prev^T),
//        [2]=OT (stim_out^T), [3]=RT (rec_out^T)
// ---------------------------------------------------------------------------
__global__ __launch_bounds__(256) void k_reduce(
    const float* __restrict__ Psum,
    const float* __restrict__ stim, const float* __restrict__ prev,
    float* __restrict__ P_relu, ushort_t* __restrict__ Tbuf, int ns)
{
    int idx = blockIdx.x * 256 + threadIdx.x;      // 0 .. 262143
    int gemm = idx >> 17;
    int r    = idx & 131071;
    int b    = r >> 12;
    int d    = r & 4095;
    float s = 0.f;
    for (int sl = 0; sl < ns; sl++)
        s += Psum[((size_t)sl * 2 + gemm) * 131072 + r];
    s = fmaxf(s, 0.f);
    P_relu[idx] = s;
    Tbuf[(2 + gemm) * 131072 + d * 32 + b] = f2bfu(s);                 // OT / RT
    Tbuf[gemm * 131072 + d * 32 + b] = f2bfu((gemm ? prev : stim)[r]); // ST / PT
}

// ---------------------------------------------------------------------------
// K3: rec_norm = LN(rec_out) per batch row; final = stim_out + rec_norm.
// ---------------------------------------------------------------------------
__global__ __launch_bounds__(256) void k_final_ln(
    const float* __restrict__ P_relu,
    const float* __restrict__ g, const float* __restrict__ be,
    float* __restrict__ dout, float* __restrict__ finalf32)
{
    __shared__ float red[256], red2[256];
    int b = blockIdx.x, tid = threadIdx.x;
    const float* rec = P_relu + 131072 + b * D_;
    const float* stm = P_relu + b * D_;

    float s = 0.f, s2 = 0.f;
    for (int d = tid; d < D_; d += 256) { float x = rec[d]; s += x; s2 += x * x; }
    red[tid] = s; red2[tid] = s2; __syncthreads();
    for (int st = 128; st > 0; st >>= 1) {
        if (tid < st) { red[tid] += red[tid + st]; red2[tid] += red2[tid + st]; }
        __syncthreads();
    }
    float m = red[0] * (1.f / D_);
    float v = red2[0] * (1.f / D_) - m * m;
    float rstd = rsqrtf(v + 1e-5f);

    for (int d = tid; d < D_; d += 256) {
        float fn = stm[d] + (rec[d] - m) * rstd * g[d] + be[d];
        finalf32[b * D_ + d] = fn;
        dout[b * D_ + d] = fn;
    }
}

// ---------------------------------------------------------------------------
// K4: fc1 GEMM  z1[b][j] = sum_k final[b][k]*fc1w[k][j], K-split by 64.
// ---------------------------------------------------------------------------
__global__ __launch_bounds__(256) void k_fc1(
    const float* __restrict__ finalf32, const float* __restrict__ fc1w,
    float* __restrict__ z1p)
{
    int kc = blockIdx.x;
    int t  = threadIdx.x;
    int k0 = kc * 64;
    const float2* W2 = (const float2*)fc1w;

    float a0[32], a1[32];
#pragma unroll
    for (int b = 0; b < 32; b++) { a0[b] = 0.f; a1[b] = 0.f; }

    for (int k = k0; k < k0 + 64; k++) {
        float2 wv = W2[k * (H1_ / 2) + t];
#pragma unroll
        for (int b = 0; b < 32; b++) {
            float a = finalf32[b * D_ + k];        // uniform -> s_load
            a0[b] = fmaf(a, wv.x, a0[b]);
            a1[b] = fmaf(a, wv.y, a1[b]);
        }
    }
    float* P = z1p + (size_t)kc * 32 * H1_;
#pragma unroll
    for (int b = 0; b < 32; b++) {
        P[b * H1_ + 2 * t]     = a0[b];
        P[b * H1_ + 2 * t + 1] = a1[b];
    }
}

// ---------------------------------------------------------------------------
// K5: MLP tail per batch row.
// ---------------------------------------------------------------------------
__global__ __launch_bounds__(256) void k_tail(
    const float* __restrict__ z1p,
    const float* __restrict__ fc1b,
    const float* __restrict__ ln1g, const float* __restrict__ ln1b,
    const float* __restrict__ fc2w, const float* __restrict__ fc2b,
    const float* __restrict__ ln2g, const float* __restrict__ ln2b,
    const float* __restrict__ fc3w, const float* __restrict__ fc3b,
    const float* __restrict__ lnog, const float* __restrict__ lnob,
    float* __restrict__ tanhout)
{
    __shared__ float sm[512];
    __shared__ float red[256], red2[256];
    __shared__ float h2s[256];
    int b = blockIdx.x, tid = threadIdx.x;

    for (int j = tid; j < H1_; j += 256) {
        float s = fc1b[j];
        for (int c = 0; c < 64; c++)
            s += z1p[((size_t)c * 32 + b) * H1_ + j];
        sm[j] = s;
    }
    __syncthreads();

    float s = 0.f, s2 = 0.f;
    for (int j = tid; j < H1_; j += 256) { float x = sm[j]; s += x; s2 += x * x; }
    red[tid] = s; red2[tid] = s2; __syncthreads();
    for (int st = 128; st > 0; st >>= 1) {
        if (tid < st) { red[tid] += red[tid + st]; red2[tid] += red2[tid + st]; }
        __syncthreads();
    }
    float m = red[0] * (1.f / H1_);
    float v = red2[0] * (1.f / H1_) - m * m;
    float rstd = rsqrtf(v + 1e-5f);
    __syncthreads();
    for (int j = tid; j < H1_; j += 256) {
        float h = (sm[j] - m) * rstd * ln1g[j] + ln1b[j];
        sm[j] = fmaxf(h, 0.f);
    }
    __syncthreads();

    float acc = fc2b[tid];
    for (int k = 0; k < H1_; k++)
        acc = fmaf(sm[k], fc2w[k * H2_ + tid], acc);
    red[tid] = acc; red2[tid] = acc * acc; __syncthreads();
    for (int st = 128; st > 0; st >>= 1) {
        if (tid < st) { red[tid] += red[tid + st]; red2[tid] += red2[tid + st]; }
        __syncthreads();
    }
    float m2 = red[0] * (1.f / H2_);
    float v2 = red2[0] * (1.f / H2_) - m2 * m2;
    float rstd2 = rsqrtf(v2 + 1e-5f);
    float h2 = fmaxf((acc - m2) * rstd2 * ln2g[tid] + ln2b[tid], 0.f);
    __syncthreads();
    h2s[tid] = h2; __syncthreads();

    int j  = tid & 63;
    int ks = tid >> 6;
    float p = 0.f;
    for (int kk = 0; kk < 64; kk++) {
        int k = ks * 64 + kk;
        p = fmaf(h2s[k], fc3w[k * U_ + j], p);
    }
    red[tid] = p; __syncthreads();
    if (tid < 64) {
        float x = red[tid] + red[tid + 64] + red[tid + 128] + red[tid + 192]
                + fc3b[tid];
        float ss = x, qq = x * x;
#pragma unroll
        for (int off = 32; off; off >>= 1) {
            ss += __shfl_xor(ss, off, 64);
            qq += __shfl_xor(qq, off, 64);
        }
        float m3 = ss * (1.f / U_);
        float v3 = qq * (1.f / U_) - m3 * m3;
        float to = tanhf((x - m3) * rsqrtf(v3 + 1e-5f) * lnog[tid] + lnob[tid]);
        tanhout[b * U_ + tid] = to;
    }
}

// ---------------------------------------------------------------------------
// K6: weight update + row L2 normalize (unchanged).
// ---------------------------------------------------------------------------
__global__ __launch_bounds__(256) void k_update(
    const float* __restrict__ Wheb, const float* __restrict__ Wrec,
    const float* __restrict__ decay, const float* __restrict__ tanhout,
    const ushort_t* __restrict__ Tbuf, float* __restrict__ dout)
{
    __shared__ ushort_t cache[8 * 4096];   // 64 KB
    int bx = blockIdx.x;
    int mat   = bx >> 9;
    int itile = bx & 511;
    int i0    = itile * 8;
    int tid  = threadIdx.x;
    int wv   = tid >> 6;
    int lane = tid & 63;
    int ir0 = i0 + wv * 2, ir1 = ir0 + 1;

    float al = 0.f;
#pragma unroll
    for (int b = 0; b < 32; b++) al += tanhout[b * U_ + lane];
    al *= (9.9f / 32.f);

    const ushort_t* Sp = Tbuf + mat * 131072;
    const uint4* s0p = (const uint4*)(Sp + (size_t)ir0 * 32);
    const uint4* s1p = (const uint4*)(Sp + (size_t)ir1 * 32);
    float st0[32], st1[32];
#pragma unroll
    for (int q = 0; q < 4; q++) {
        uint4 a = s0p[q], c = s1p[q];
        const uint32_t aw[4] = {a.x, a.y, a.z, a.w};
        const uint32_t cw[4] = {c.x, c.y, c.z, c.w};
#pragma unroll
        for (int e = 0; e < 4; e++) {
            st0[q * 8 + 2 * e]     = __uint_as_float(aw[e] << 16);
            st0[q * 8 + 2 * e + 1] = __uint_as_float(aw[e] & 0xffff0000u);
            st1[q * 8 + 2 * e]     = __uint_as_float(cw[e] << 16);
            st1[q * 8 + 2 * e + 1] = __uint_as_float(cw[e] & 0xffff0000u);
        }
    }
    float dc0 = 1.f - decay[ir0];
    float dc1 = 1.f - decay[ir1];

    const ushort_t* Op = Tbuf + (2 + mat) * 131072;
    const float* Wp = mat ? Wrec : Wheb;

    float ss0 = 0.f, ss1 = 0.f;
    for (int jt = 0; jt < 64; jt++) {
        int j = jt * 64 + lane;
        float av = __shfl(al, jt, 64);
        const uint4* op = (const uint4*)(Op + (size_t)j * 32);
        float u0 = 0.f, u1 = 0.f;
#pragma unroll
        for (int q = 0; q < 4; q++) {
            uint4 a = op[q];
            const uint32_t w4[4] = {a.x, a.y, a.z, a.w};
#pragma unroll
            for (int e = 0; e < 4; e++) {
                float o0 = __uint_as_float(w4[e] << 16);
                float o1 = __uint_as_float(w4[e] & 0xffff0000u);
                u0 = fmaf(st0[q * 8 + 2 * e], o0, u0);
                u0 = fmaf(st0[q * 8 + 2 * e + 1], o1, u0);
                u1 = fmaf(st1[q * 8 + 2 * e], o0, u1);
                u1 = fmaf(st1[q * 8 + 2 * e + 1], o1, u1);
            }
        }
        float w0v = Wp[(size_t)ir0 * D_ + j];
        float w1v = Wp[(size_t)ir1 * D_ + j];
        float v0 = (w0v + av * u0) * dc0;
        float v1 = (w1v + av * u1) * dc1;
        ss0 += v0 * v0;
        ss1 += v1 * v1;
        cache[(wv * 2) * 4096 + j]     = f2bfu(v0);
        cache[(wv * 2 + 1) * 4096 + j] = f2bfu(v1);
    }
#pragma unroll
    for (int off = 32; off; off >>= 1) {
        ss0 += __shfl_xor(ss0, off, 64);
        ss1 += __shfl_xor(ss1, off, 64);
    }
    float ri0 = 1.f / fmaxf(sqrtf(ss0), 1e-12f);
    float ri1 = 1.f / fmaxf(sqrtf(ss1), 1e-12f);

    float* O0 = dout + (size_t)(32 + mat * D_ + ir0) * D_;
    float* O1 = O0 + D_;
    for (int j = lane; j < D_; j += 64) {
        O0[j] = bf2f(cache[(wv * 2) * 4096 + j]) * ri0;
        O1[j] = bf2f(cache[(wv * 2 + 1) * 4096 + j]) * ri1;
    }
}

// ---------------------------------------------------------------------------
extern "C" void kernel_launch(void* const* d_in, const int* in_sizes, int n_in,
                              void* d_out, int out_size, void* d_ws, size_t ws_size,
                              hipStream_t stream)
{
    const float* stim = (const float*)d_in[0];
    const float* prev = (const float*)d_in[1];
    const float* Wheb = (const float*)d_in[2];
    const float* Wrec = (const float*)d_in[3];
    const float* decay= (const float*)d_in[4];
    const float* lnrg = (const float*)d_in[5];
    const float* lnrb = (const float*)d_in[6];
    const float* fc1w = (const float*)d_in[7];
    const float* fc1b = (const float*)d_in[8];
    const float* ln1g = (const float*)d_in[9];
    const float* ln1b = (const float*)d_in[10];
    const float* fc2w = (const float*)d_in[11];
    const float* fc2b = (const float*)d_in[12];
    const float* ln2g = (const float*)d_in[13];
    const float* ln2b = (const float*)d_in[14];
    const float* fc3w = (const float*)d_in[15];
    const float* fc3b = (const float*)d_in[16];
    const float* lnog = (const float*)d_in[17];
    const float* lnob = (const float*)d_in[18];

    // Fixed-tail workspace: P_relu(1MB) Tbuf(1MB) P_final(512KB) z1p(4MB) tanh(8KB)
    const size_t FIXED = 1048576u + 1048576u + 524288u + 4194304u + 8192u; // 6823936
    // Slice count for K-split partials: 1 MB per slice, up to 16 (no atomics).
    int ns = 16;
    if (ws_size < FIXED + 16u * 1048576u) {
        size_t avail = (ws_size > FIXED) ? (ws_size - FIXED) / 1048576u : 1u;
        ns = (int)avail;
        if (ns < 1) ns = 1;
        if (ns > 16) ns = 16;
    }

    char* ws = (char*)d_ws;
    float*    P_sum   = (float*)(ws + 0);                 // ns MB  [ns][2][32][4096]
    char*     rest    = ws + (size_t)ns * 1048576u;
    float*    P_relu  = (float*)(rest + 0);               // 1 MB   [2][32][4096]
    ushort_t* P_tbuf  = (ushort_t*)(rest + 1048576);      // 1 MB   ST,PT,OT,RT (bf16)
    float*    P_final = (float*)(rest + 2097152);         // 512 KB [32][4096]
    float*    P_z1p   = (float*)(rest + 2621440);         // 4 MB   [64][32][512]
    float*    P_tanh  = (float*)(rest + 6815744);         // 8 KB   [32][64]

    float* out = (float*)d_out;

    if (ns < 16)  // atomic fallback needs zeroed partials
        hipMemsetAsync(P_sum, 0, (size_t)ns * 1048576u, stream);

    k_gemm_mfma<<<1024, 256, 0, stream>>>(stim, prev, Wheb, Wrec, P_sum, ns);
    k_reduce   <<<1024, 256, 0, stream>>>(P_sum, stim, prev, P_relu, P_tbuf, ns);
    k_final_ln <<<32,   256, 0, stream>>>(P_relu, lnrg, lnrb, out, P_final);
    k_fc1      <<<64,   256, 0, stream>>>(P_final, fc1w, P_z1p);
    k_tail     <<<32,   256, 0, stream>>>(P_z1p, fc1b, ln1g, ln1b, fc2w, fc2b,
                                          ln2g, ln2b, fc3w, fc3b, lnog, lnob, P_tanh);
    k_update   <<<1024, 256, 0, stream>>>(Wheb, Wrec, decay, P_tanh, P_tbuf, out);
}

// Round 2
// 409.354 us; speedup vs baseline: 1.1701x; 1.0381x over previous
//
#include <hip/hip_runtime.h>
#include <stdint.h>

typedef unsigned short ushort_t;
typedef float f32x4 __attribute__((ext_vector_type(4)));
typedef short s16x8 __attribute__((ext_vector_type(8)));

#define B_  32
#define D_  4096
#define H1_ 512
#define H2_ 256
#define U_  64

#define KS_   16        // K-splits for forward GEMM
#define KCH_  256       // K per block (4096/16)
#define NT_   128       // N tile per block
#define APAD  264       // A_lds row stride (u16): 256 + 8 (16B aligned)
#define WPAD  72        // Wt_lds row stride (u16): 64 + 8 (16B aligned)

__device__ __forceinline__ float bf2f(ushort_t u) {
    return __uint_as_float(((uint32_t)u) << 16);
}
__device__ __forceinline__ ushort_t f2bfu(float f) {  // RNE float->bf16 bits
    uint32_t x = __float_as_uint(f);
    return (ushort_t)((x + 0x7fffu + ((x >> 16) & 1u)) >> 16);
}
__device__ __forceinline__ uint32_t pk2bf(float a, float b) {
    return ((uint32_t)f2bfu(a)) | (((uint32_t)f2bfu(b)) << 16);
}

// ---------------------------------------------------------------------------
// K1: forward GEMMs via MFMA 16x16x32 bf16.
// C[b][n] = sum_k A[b][k] * W[k][n], A=[32 x 4096] fp32, W=[4096 x 4096] fp32.
// grid 1024: [gemm(2)][nblk(32)][kchunk(16)].  Block: 256 thr = 4 waves.
// K-split partials: when ns==16 each chunk writes its OWN Psum slice with
// plain stores (no atomics); ns<16 falls back to atomicAdd into chunk%ns.
// ---------------------------------------------------------------------------
__global__ __launch_bounds__(256, 4) void k_gemm_mfma(
    const float* __restrict__ stim, const float* __restrict__ prev,
    const float* __restrict__ Wheb, const float* __restrict__ Wrec,
    float* __restrict__ Psum, int ns)
{
    __shared__ ushort_t Al[32 * APAD];     // 16.5 KB
    __shared__ ushort_t Wt[NT_ * WPAD];    // 18.0 KB

    int bx = blockIdx.x;
    int gemm  = bx >> 9;
    int rem   = bx & 511;
    int nblk  = rem >> 4;
    int chunk = rem & 15;
    const float* A = gemm ? prev : stim;
    const float* W = gemm ? Wrec : Wheb;
    int k0c = chunk * KCH_;
    int n0  = nblk * NT_;
    int tid = threadIdx.x, lane = tid & 63, wave = tid >> 6;
    int col = lane & 15, quad = lane >> 4;

    // ---- stage A [32][256] fp32 -> bf16 LDS (once per block)
#pragma unroll
    for (int p = 0; p < 16; p++) {
        int idx = p * 256 + tid;           // over [32][128] float2
        int b   = idx >> 7;
        int kk  = (idx & 127) * 2;
        float2 v = *(const float2*)(A + (size_t)b * D_ + k0c + kk);
        *(uint32_t*)&Al[b * APAD + kk] = pk2bf(v.x, v.y);
    }

    f32x4 acc[2][2];
#pragma unroll
    for (int mt = 0; mt < 2; mt++)
#pragma unroll
        for (int nt = 0; nt < 2; nt++)
            acc[mt][nt] = (f32x4){0.f, 0.f, 0.f, 0.f};

    int wcol = tid & 127;                  // column within N tile
    int kh   = (tid >> 7) * 32;            // k offset within kstep (0 or 32)

    // ---- K loop: 4 ksteps of 64
    for (int ks = 0; ks < 4; ks++) {
        __syncthreads();                   // protect Wt before overwrite
        // stage W kstep: 2 threads per column, 32 k each (16 bf16 pairs)
        const float* Wc = W + (size_t)(k0c + ks * 64 + kh) * D_ + n0 + wcol;
        uint32_t* dst = (uint32_t*)&Wt[wcol * WPAD] + (kh >> 1);
#pragma unroll
        for (int i = 0; i < 16; i++) {
            float a = Wc[(size_t)(2 * i) * D_];
            float b = Wc[(size_t)(2 * i + 1) * D_];
            dst[i] = pk2bf(a, b);
        }
        __syncthreads();

#pragma unroll
        for (int kq = 0; kq < 2; kq++) {
            int kb = ks * 64 + kq * 32 + quad * 8;   // k in A_lds chunk
            int kw = kq * 32 + quad * 8;             // k in Wt row
            s16x8 af[2], bf[2];
            af[0] = *(const s16x8*)&Al[col * APAD + kb];
            af[1] = *(const s16x8*)&Al[(col + 16) * APAD + kb];
#pragma unroll
            for (int nt = 0; nt < 2; nt++)
                bf[nt] = *(const s16x8*)&Wt[(wave * 32 + nt * 16 + col) * WPAD + kw];
#pragma unroll
            for (int mt = 0; mt < 2; mt++)
#pragma unroll
                for (int nt = 0; nt < 2; nt++)
                    acc[mt][nt] = __builtin_amdgcn_mfma_f32_16x16x32_bf16(
                        af[mt], bf[nt], acc[mt][nt], 0, 0, 0);
        }
    }

    // ---- epilogue: write K-split partials to this chunk's slice
    int slice = chunk % ns;                // ns==16 -> slice==chunk (exclusive)
    float* P = Psum + ((size_t)slice * 2 + gemm) * 32 * D_;
    if (ns == 16) {
#pragma unroll
        for (int mt = 0; mt < 2; mt++)
#pragma unroll
            for (int nt = 0; nt < 2; nt++)
#pragma unroll
                for (int r = 0; r < 4; r++) {
                    int b = mt * 16 + quad * 4 + r;
                    int n = n0 + wave * 32 + nt * 16 + col;
                    P[(size_t)b * D_ + n] = acc[mt][nt][r];
                }
    } else {
#pragma unroll
        for (int mt = 0; mt < 2; mt++)
#pragma unroll
            for (int nt = 0; nt < 2; nt++)
#pragma unroll
                for (int r = 0; r < 4; r++) {
                    int b = mt * 16 + quad * 4 + r;
                    int n = n0 + wave * 32 + nt * 16 + col;
                    atomicAdd(&P[(size_t)b * D_ + n], acc[mt][nt][r]);
                }
    }
}

// ---------------------------------------------------------------------------
// K2: sum slices + relu -> P_relu (fp32) + build bf16 transposed copies:
//   Tbuf sections of 4096*32 u16: [0]=ST (stim^T), [1]=PT (prev^T),
//        [2]=OT (stim_out^T), [3]=RT (rec_out^T)
// ---------------------------------------------------------------------------
__global__ __launch_bounds__(256) void k_reduce(
    const float* __restrict__ Psum,
    const float* __restrict__ stim, const float* __restrict__ prev,
    float* __restrict__ P_relu, ushort_t* __restrict__ Tbuf, int ns)
{
    int idx = blockIdx.x * 256 + threadIdx.x;      // 0 .. 262143
    int gemm = idx >> 17;
    int r    = idx & 131071;
    int b    = r >> 12;
    int d    = r & 4095;
    float s = 0.f;
    for (int sl = 0; sl < ns; sl++)
        s += Psum[((size_t)sl * 2 + gemm) * 131072 + r];
    s = fmaxf(s, 0.f);
    P_relu[idx] = s;
    Tbuf[(2 + gemm) * 131072 + d * 32 + b] = f2bfu(s);                 // OT / RT
    Tbuf[gemm * 131072 + d * 32 + b] = f2bfu((gemm ? prev : stim)[r]); // ST / PT
}

// ---------------------------------------------------------------------------
// K3: rec_norm = LN(rec_out) per batch row; final = stim_out + rec_norm.
// ---------------------------------------------------------------------------
__global__ __launch_bounds__(256) void k_final_ln(
    const float* __restrict__ P_relu,
    const float* __restrict__ g, const float* __restrict__ be,
    float* __restrict__ dout, float* __restrict__ finalf32)
{
    __shared__ float red[256], red2[256];
    int b = blockIdx.x, tid = threadIdx.x;
    const float* rec = P_relu + 131072 + b * D_;
    const float* stm = P_relu + b * D_;

    float s = 0.f, s2 = 0.f;
    for (int d = tid; d < D_; d += 256) { float x = rec[d]; s += x; s2 += x * x; }
    red[tid] = s; red2[tid] = s2; __syncthreads();
    for (int st = 128; st > 0; st >>= 1) {
        if (tid < st) { red[tid] += red[tid + st]; red2[tid] += red2[tid + st]; }
        __syncthreads();
    }
    float m = red[0] * (1.f / D_);
    float v = red2[0] * (1.f / D_) - m * m;
    float rstd = rsqrtf(v + 1e-5f);

    for (int d = tid; d < D_; d += 256) {
        float fn = stm[d] + (rec[d] - m) * rstd * g[d] + be[d];
        finalf32[b * D_ + d] = fn;
        dout[b * D_ + d] = fn;
    }
}

// ---------------------------------------------------------------------------
// K4: fc1 GEMM  z1[b][j] = sum_k final[b][k]*fc1w[k][j], K-split by 64.
// ---------------------------------------------------------------------------
__global__ __launch_bounds__(256) void k_fc1(
    const float* __restrict__ finalf32, const float* __restrict__ fc1w,
    float* __restrict__ z1p)
{
    int kc = blockIdx.x;
    int t  = threadIdx.x;
    int k0 = kc * 64;
    const float2* W2 = (const float2*)fc1w;

    float a0[32], a1[32];
#pragma unroll
    for (int b = 0; b < 32; b++) { a0[b] = 0.f; a1[b] = 0.f; }

    for (int k = k0; k < k0 + 64; k++) {
        float2 wv = W2[k * (H1_ / 2) + t];
#pragma unroll
        for (int b = 0; b < 32; b++) {
            float a = finalf32[b * D_ + k];        // uniform -> s_load
            a0[b] = fmaf(a, wv.x, a0[b]);
            a1[b] = fmaf(a, wv.y, a1[b]);
        }
    }
    float* P = z1p + (size_t)kc * 32 * H1_;
#pragma unroll
    for (int b = 0; b < 32; b++) {
        P[b * H1_ + 2 * t]     = a0[b];
        P[b * H1_ + 2 * t + 1] = a1[b];
    }
}

// ---------------------------------------------------------------------------
// K5: MLP tail per batch row.
// ---------------------------------------------------------------------------
__global__ __launch_bounds__(256) void k_tail(
    const float* __restrict__ z1p,
    const float* __restrict__ fc1b,
    const float* __restrict__ ln1g, const float* __restrict__ ln1b,
    const float* __restrict__ fc2w, const float* __restrict__ fc2b,
    const float* __restrict__ ln2g, const float* __restrict__ ln2b,
    const float* __restrict__ fc3w, const float* __restrict__ fc3b,
    const float* __restrict__ lnog, const float* __restrict__ lnob,
    float* __restrict__ tanhout)
{
    __shared__ float sm[512];
    __shared__ float red[256], red2[256];
    __shared__ float h2s[256];
    int b = blockIdx.x, tid = threadIdx.x;

    for (int j = tid; j < H1_; j += 256) {
        float s = fc1b[j];
        for (int c = 0; c < 64; c++)
            s += z1p[((size_t)c * 32 + b) * H1_ + j];
        sm[j] = s;
    }
    __syncthreads();

    float s = 0.f, s2 = 0.f;
    for (int j = tid; j < H1_; j += 256) { float x = sm[j]; s += x; s2 += x * x; }
    red[tid] = s; red2[tid] = s2; __syncthreads();
    for (int st = 128; st > 0; st >>= 1) {
        if (tid < st) { red[tid] += red[tid + st]; red2[tid] += red2[tid + st]; }
        __syncthreads();
    }
    float m = red[0] * (1.f / H1_);
    float v = red2[0] * (1.f / H1_) - m * m;
    float rstd = rsqrtf(v + 1e-5f);
    __syncthreads();
    for (int j = tid; j < H1_; j += 256) {
        float h = (sm[j] - m) * rstd * ln1g[j] + ln1b[j];
        sm[j] = fmaxf(h, 0.f);
    }
    __syncthreads();

    float acc = fc2b[tid];
    for (int k = 0; k < H1_; k++)
        acc = fmaf(sm[k], fc2w[k * H2_ + tid], acc);
    red[tid] = acc; red2[tid] = acc * acc; __syncthreads();
    for (int st = 128; st > 0; st >>= 1) {
        if (tid < st) { red[tid] += red[tid + st]; red2[tid] += red2[tid + st]; }
        __syncthreads();
    }
    float m2 = red[0] * (1.f / H2_);
    float v2 = red2[0] * (1.f / H2_) - m2 * m2;
    float rstd2 = rsqrtf(v2 + 1e-5f);
    float h2 = fmaxf((acc - m2) * rstd2 * ln2g[tid] + ln2b[tid], 0.f);
    __syncthreads();
    h2s[tid] = h2; __syncthreads();

    int j  = tid & 63;
    int ks = tid >> 6;
    float p = 0.f;
    for (int kk = 0; kk < 64; kk++) {
        int k = ks * 64 + kk;
        p = fmaf(h2s[k], fc3w[k * U_ + j], p);
    }
    red[tid] = p; __syncthreads();
    if (tid < 64) {
        float x = red[tid] + red[tid + 64] + red[tid + 128] + red[tid + 192]
                + fc3b[tid];
        float ss = x, qq = x * x;
#pragma unroll
        for (int off = 32; off; off >>= 1) {
            ss += __shfl_xor(ss, off, 64);
            qq += __shfl_xor(qq, off, 64);
        }
        float m3 = ss * (1.f / U_);
        float v3 = qq * (1.f / U_) - m3 * m3;
        float to = tanhf((x - m3) * rsqrtf(v3 + 1e-5f) * lnog[tid] + lnob[tid]);
        tanhout[b * U_ + tid] = to;
    }
}

// ---------------------------------------------------------------------------
// K6: weight update + row L2 normalize via MFMA.
// upd[i][j] = sum_b A[b][i]*Aout[b][j]  ==  ST[i][b] (A-frag) x OT[j][b] (B-frag)
// grid 512 = [mat(2)][row-tile(256)], block 512 thr = 8 waves.
// Each block: 16 rows x 4096 cols.  Wave w owns j-tiles jt%8==w (32 tiles).
// One mfma_16x16x32 per tile (K=32=batch, single instruction).
// v = (W + alpha_j*u)*dc_i cached as packed bf16 in regs (fully unrolled,
// static indices -> no scratch).  Row ss: shfl_xor over 16 cols + LDS over
// 8 waves.  Sweep 2 unpacks, scales by 1/||row||, stores.
// ---------------------------------------------------------------------------
__global__ __launch_bounds__(512, 2) void k_update(
    const float* __restrict__ Wheb, const float* __restrict__ Wrec,
    const float* __restrict__ decay, const float* __restrict__ tanhout,
    const ushort_t* __restrict__ Tbuf, float* __restrict__ dout)
{
    __shared__ float ssl[8][16];
    int bx   = blockIdx.x;          // 512 = 2 mats x 256 row-tiles
    int mat  = bx >> 8;
    int i0   = (bx & 255) * 16;
    int tid  = threadIdx.x;
    int wave = tid >> 6, lane = tid & 63;
    int col  = lane & 15, quad = lane >> 4;

    // alpha per 64-wide j-group (lane index == group index)
    float al = 0.f;
#pragma unroll
    for (int b = 0; b < 32; b++) al += tanhout[b * U_ + lane];
    al *= (9.9f / 32.f);

    const ushort_t* Sp = Tbuf + mat * 131072;        // ST / PT  [i][b]
    const ushort_t* Op = Tbuf + (2 + mat) * 131072;  // OT / RT  [j][b]
    const float*    Wp = mat ? Wrec : Wheb;

    // A-frag constant across j: A[row=col][k=quad*8+e] = Sp[(i0+col)*32 + quad*8]
    s16x8 af = *(const s16x8*)&Sp[(i0 + col) * 32 + quad * 8];

    float dc[4];
#pragma unroll
    for (int r = 0; r < 4; r++) dc[r] = 1.f - decay[i0 + quad * 4 + r];

    uint32_t vc[32][2];             // packed bf16 cache: v[0..3] per tile
    float ss[4] = {0.f, 0.f, 0.f, 0.f};

#pragma unroll
    for (int t = 0; t < 32; t++) {
        int j0 = (t * 8 + wave) * 16;
        float av = __shfl(al, j0 >> 6, 64);     // uniform broadcast
        s16x8 bfr = *(const s16x8*)&Op[(j0 + col) * 32 + quad * 8];
        f32x4 u = (f32x4){0.f, 0.f, 0.f, 0.f};
        u = __builtin_amdgcn_mfma_f32_16x16x32_bf16(af, bfr, u, 0, 0, 0);
        const float* wrow = Wp + (size_t)(i0 + quad * 4) * D_ + j0 + col;
        float v0 = fmaf(av, u[0], wrow[0])              * dc[0];
        float v1 = fmaf(av, u[1], wrow[(size_t)1 * D_]) * dc[1];
        float v2 = fmaf(av, u[2], wrow[(size_t)2 * D_]) * dc[2];
        float v3 = fmaf(av, u[3], wrow[(size_t)3 * D_]) * dc[3];
        ss[0] = fmaf(v0, v0, ss[0]);
        ss[1] = fmaf(v1, v1, ss[1]);
        ss[2] = fmaf(v2, v2, ss[2]);
        ss[3] = fmaf(v3, v3, ss[3]);
        vc[t][0] = pk2bf(v0, v1);
        vc[t][1] = pk2bf(v2, v3);
    }

    // reduce ss across the 16 cols sharing this quad (lanes quad*16..+15)
#pragma unroll
    for (int off = 8; off; off >>= 1) {
#pragma unroll
        for (int r = 0; r < 4; r++) ss[r] += __shfl_xor(ss[r], off, 64);
    }
    if (col == 0) {
#pragma unroll
        for (int r = 0; r < 4; r++) ssl[wave][quad * 4 + r] = ss[r];
    }
    __syncthreads();
    float ri[4];
#pragma unroll
    for (int r = 0; r < 4; r++) {
        float s = 0.f;
#pragma unroll
        for (int w = 0; w < 8; w++) s += ssl[w][quad * 4 + r];
        ri[r] = 1.f / fmaxf(sqrtf(s), 1e-12f);
    }

    float* O = dout + (size_t)(32 + mat * D_ + i0 + quad * 4) * D_;
#pragma unroll
    for (int t = 0; t < 32; t++) {
        int j0 = (t * 8 + wave) * 16;
        float v0 = __uint_as_float(vc[t][0] << 16);
        float v1 = __uint_as_float(vc[t][0] & 0xffff0000u);
        float v2 = __uint_as_float(vc[t][1] << 16);
        float v3 = __uint_as_float(vc[t][1] & 0xffff0000u);
        O[j0 + col]                   = v0 * ri[0];
        O[(size_t)1 * D_ + j0 + col]  = v1 * ri[1];
        O[(size_t)2 * D_ + j0 + col]  = v2 * ri[2];
        O[(size_t)3 * D_ + j0 + col]  = v3 * ri[3];
    }
}

// ---------------------------------------------------------------------------
extern "C" void kernel_launch(void* const* d_in, const int* in_sizes, int n_in,
                              void* d_out, int out_size, void* d_ws, size_t ws_size,
                              hipStream_t stream)
{
    const float* stim = (const float*)d_in[0];
    const float* prev = (const float*)d_in[1];
    const float* Wheb = (const float*)d_in[2];
    const float* Wrec = (const float*)d_in[3];
    const float* decay= (const float*)d_in[4];
    const float* lnrg = (const float*)d_in[5];
    const float* lnrb = (const float*)d_in[6];
    const float* fc1w = (const float*)d_in[7];
    const float* fc1b = (const float*)d_in[8];
    const float* ln1g = (const float*)d_in[9];
    const float* ln1b = (const float*)d_in[10];
    const float* fc2w = (const float*)d_in[11];
    const float* fc2b = (const float*)d_in[12];
    const float* ln2g = (const float*)d_in[13];
    const float* ln2b = (const float*)d_in[14];
    const float* fc3w = (const float*)d_in[15];
    const float* fc3b = (const float*)d_in[16];
    const float* lnog = (const float*)d_in[17];
    const float* lnob = (const float*)d_in[18];

    // Fixed-tail workspace: P_relu(1MB) Tbuf(1MB) P_final(512KB) z1p(4MB) tanh(8KB)
    const size_t FIXED = 1048576u + 1048576u + 524288u + 4194304u + 8192u; // 6823936
    // Slice count for K-split partials: 1 MB per slice, up to 16 (no atomics).
    int ns = 16;
    if (ws_size < FIXED + 16u * 1048576u) {
        size_t avail = (ws_size > FIXED) ? (ws_size - FIXED) / 1048576u : 1u;
        ns = (int)avail;
        if (ns < 1) ns = 1;
        if (ns > 16) ns = 16;
    }

    char* ws = (char*)d_ws;
    float*    P_sum   = (float*)(ws + 0);                 // ns MB  [ns][2][32][4096]
    char*     rest    = ws + (size_t)ns * 1048576u;
    float*    P_relu  = (float*)(rest + 0);               // 1 MB   [2][32][4096]
    ushort_t* P_tbuf  = (ushort_t*)(rest + 1048576);      // 1 MB   ST,PT,OT,RT (bf16)
    float*    P_final = (float*)(rest + 2097152);         // 512 KB [32][4096]
    float*    P_z1p   = (float*)(rest + 2621440);         // 4 MB   [64][32][512]
    float*    P_tanh  = (float*)(rest + 6815744);         // 8 KB   [32][64]

    float* out = (float*)d_out;

    if (ns < 16)  // atomic fallback needs zeroed partials
        hipMemsetAsync(P_sum, 0, (size_t)ns * 1048576u, stream);

    k_gemm_mfma<<<1024, 256, 0, stream>>>(stim, prev, Wheb, Wrec, P_sum, ns);
    k_reduce   <<<1024, 256, 0, stream>>>(P_sum, stim, prev, P_relu, P_tbuf, ns);
    k_final_ln <<<32,   256, 0, stream>>>(P_relu, lnrg, lnrb, out, P_final);
    k_fc1      <<<64,   256, 0, stream>>>(P_final, fc1w, P_z1p);
    k_tail     <<<32,   256, 0, stream>>>(P_z1p, fc1b, ln1g, ln1b, fc2w, fc2b,
                                          ln2g, ln2b, fc3w, fc3b, lnog, lnob, P_tanh);
    k_update   <<<512,  512, 0, stream>>>(Wheb, Wrec, decay, P_tanh, P_tbuf, out);
}

// Round 3
// 403.249 us; speedup vs baseline: 1.1878x; 1.0151x over previous
//
#include <hip/hip_runtime.h>
#include <stdint.h>

typedef unsigned short ushort_t;
typedef float f32x4 __attribute__((ext_vector_type(4)));
typedef short s16x8 __attribute__((ext_vector_type(8)));

#define B_  32
#define D_  4096
#define H1_ 512
#define H2_ 256
#define U_  64

#define KS_   16        // K-splits for forward GEMM
#define KCH_  256       // K per block (4096/16)
#define NT_   128       // N tile per block
#define APAD  264       // A_lds row stride (u16): 256 + 8 (16B aligned)
#define WPAD  70        // Wt_lds row stride (u16): 140B rows -> 4-way write conflict max

__device__ __forceinline__ float bf2f(ushort_t u) {
    return __uint_as_float(((uint32_t)u) << 16);
}
__device__ __forceinline__ ushort_t f2bfu(float f) {  // RNE float->bf16 bits
    uint32_t x = __float_as_uint(f);
    return (ushort_t)((x + 0x7fffu + ((x >> 16) & 1u)) >> 16);
}
__device__ __forceinline__ uint32_t pk2bf(float a, float b) {
    return ((uint32_t)f2bfu(a)) | (((uint32_t)f2bfu(b)) << 16);
}

// ---------------------------------------------------------------------------
// K1: forward GEMMs via MFMA 16x16x32 bf16.
// C[b][n] = sum_k A[b][k] * W[k][n], A=[32 x 4096] fp32, W=[4096 x 4096] fp32.
// grid 1024: [gemm(2)][nblk(32)][kchunk(16)].  Block: 256 thr = 4 waves.
// W staged with float4 row loads (16B/lane): thread owns (2 k-rows x 4 n),
// packs k-pairs to u32, scatters transposed into Wt[n][k] (WPAD=70 keeps the
// scatter at 4-way banks).  K-split partials to private Psum slices (ns==16).
// ---------------------------------------------------------------------------
__global__ __launch_bounds__(256, 4) void k_gemm_mfma(
    const float* __restrict__ stim, const float* __restrict__ prev,
    const float* __restrict__ Wheb, const float* __restrict__ Wrec,
    float* __restrict__ Psum, int ns)
{
    __shared__ ushort_t Al[32 * APAD];     // 16.5 KB
    __shared__ ushort_t Wt[NT_ * WPAD];    // 17.5 KB

    int bx = blockIdx.x;
    int gemm  = bx >> 9;
    int rem   = bx & 511;
    int nblk  = rem >> 4;
    int chunk = rem & 15;
    const float* A = gemm ? prev : stim;
    const float* W = gemm ? Wrec : Wheb;
    int k0c = chunk * KCH_;
    int n0  = nblk * NT_;
    int tid = threadIdx.x, lane = tid & 63, wave = tid >> 6;
    int col = lane & 15, quad = lane >> 4;

    // ---- stage A [32][256] fp32 -> bf16 LDS via float4 (once per block)
#pragma unroll
    for (int p = 0; p < 8; p++) {
        int idx = p * 256 + tid;           // over [32][64] float4
        int b   = idx >> 6;
        int k4  = (idx & 63) * 4;
        float4 v = *(const float4*)(A + (size_t)b * D_ + k0c + k4);
        uint2 w; w.x = pk2bf(v.x, v.y); w.y = pk2bf(v.z, v.w);
        *(uint2*)&Al[b * APAD + k4] = w;   // 8B-aligned: 528*b + 8*(idx&63)
    }

    f32x4 acc[2][2];
#pragma unroll
    for (int mt = 0; mt < 2; mt++)
#pragma unroll
        for (int nt = 0; nt < 2; nt++)
            acc[mt][nt] = (f32x4){0.f, 0.f, 0.f, 0.f};

    int m = tid & 31;                      // n4 = m*4 (n within tile)
    int g = tid >> 5;                      // kpair group 0..7

    // ---- K loop: 4 ksteps of 64
    for (int ks = 0; ks < 4; ks++) {
        __syncthreads();                   // protect Wt before overwrite
        // stage W kstep [64 k][128 n]: float4 loads, transposed u32 writes
        const float* Wb = W + (size_t)(k0c + ks * 64) * D_ + n0 + m * 4;
#pragma unroll
        for (int i = 0; i < 4; i++) {
            int kp = g + 8 * i;            // kpair 0..31
            const float* p0 = Wb + (size_t)(2 * kp) * D_;
            float4 r0 = *(const float4*)p0;
            float4 r1 = *(const float4*)(p0 + D_);
            *(uint32_t*)&Wt[(m * 4 + 0) * WPAD + 2 * kp] = pk2bf(r0.x, r1.x);
            *(uint32_t*)&Wt[(m * 4 + 1) * WPAD + 2 * kp] = pk2bf(r0.y, r1.y);
            *(uint32_t*)&Wt[(m * 4 + 2) * WPAD + 2 * kp] = pk2bf(r0.z, r1.z);
            *(uint32_t*)&Wt[(m * 4 + 3) * WPAD + 2 * kp] = pk2bf(r0.w, r1.w);
        }
        __syncthreads();

#pragma unroll
        for (int kq = 0; kq < 2; kq++) {
            int kb = ks * 64 + kq * 32 + quad * 8;   // k in A_lds chunk
            int kw = kq * 32 + quad * 8;             // k in Wt row
            s16x8 af[2], bf[2];
            af[0] = *(const s16x8*)&Al[col * APAD + kb];
            af[1] = *(const s16x8*)&Al[(col + 16) * APAD + kb];
#pragma unroll
            for (int nt = 0; nt < 2; nt++)
                bf[nt] = *(const s16x8*)&Wt[(wave * 32 + nt * 16 + col) * WPAD + kw];
#pragma unroll
            for (int mt = 0; mt < 2; mt++)
#pragma unroll
                for (int nt = 0; nt < 2; nt++)
                    acc[mt][nt] = __builtin_amdgcn_mfma_f32_16x16x32_bf16(
                        af[mt], bf[nt], acc[mt][nt], 0, 0, 0);
        }
    }

    // ---- epilogue: write K-split partials to this chunk's slice
    int slice = chunk % ns;                // ns==16 -> slice==chunk (exclusive)
    float* P = Psum + ((size_t)slice * 2 + gemm) * 32 * D_;
    if (ns == 16) {
#pragma unroll
        for (int mt = 0; mt < 2; mt++)
#pragma unroll
            for (int nt = 0; nt < 2; nt++)
#pragma unroll
                for (int r = 0; r < 4; r++) {
                    int b = mt * 16 + quad * 4 + r;
                    int n = n0 + wave * 32 + nt * 16 + col;
                    P[(size_t)b * D_ + n] = acc[mt][nt][r];
                }
    } else {
#pragma unroll
        for (int mt = 0; mt < 2; mt++)
#pragma unroll
            for (int nt = 0; nt < 2; nt++)
#pragma unroll
                for (int r = 0; r < 4; r++) {
                    int b = mt * 16 + quad * 4 + r;
                    int n = n0 + wave * 32 + nt * 16 + col;
                    atomicAdd(&P[(size_t)b * D_ + n], acc[mt][nt][r]);
                }
    }
}

// ---------------------------------------------------------------------------
// K2: sum slices + relu -> P_relu (fp32) + build bf16 transposed copies:
//   Tbuf sections of 4096*32 u16: [0]=ST (stim^T), [1]=PT (prev^T),
//        [2]=OT (stim_out^T), [3]=RT (rec_out^T)
// ---------------------------------------------------------------------------
__global__ __launch_bounds__(256) void k_reduce(
    const float* __restrict__ Psum,
    const float* __restrict__ stim, const float* __restrict__ prev,
    float* __restrict__ P_relu, ushort_t* __restrict__ Tbuf, int ns)
{
    int idx = blockIdx.x * 256 + threadIdx.x;      // 0 .. 262143
    int gemm = idx >> 17;
    int r    = idx & 131071;
    int b    = r >> 12;
    int d    = r & 4095;
    float s = 0.f;
    for (int sl = 0; sl < ns; sl++)
        s += Psum[((size_t)sl * 2 + gemm) * 131072 + r];
    s = fmaxf(s, 0.f);
    P_relu[idx] = s;
    Tbuf[(2 + gemm) * 131072 + d * 32 + b] = f2bfu(s);                 // OT / RT
    Tbuf[gemm * 131072 + d * 32 + b] = f2bfu((gemm ? prev : stim)[r]); // ST / PT
}

// ---------------------------------------------------------------------------
// K3: rec_norm = LN(rec_out) per batch row; final = stim_out + rec_norm.
// ---------------------------------------------------------------------------
__global__ __launch_bounds__(256) void k_final_ln(
    const float* __restrict__ P_relu,
    const float* __restrict__ g, const float* __restrict__ be,
    float* __restrict__ dout, float* __restrict__ finalf32)
{
    __shared__ float red[256], red2[256];
    int b = blockIdx.x, tid = threadIdx.x;
    const float* rec = P_relu + 131072 + b * D_;
    const float* stm = P_relu + b * D_;

    float s = 0.f, s2 = 0.f;
    for (int d = tid; d < D_; d += 256) { float x = rec[d]; s += x; s2 += x * x; }
    red[tid] = s; red2[tid] = s2; __syncthreads();
    for (int st = 128; st > 0; st >>= 1) {
        if (tid < st) { red[tid] += red[tid + st]; red2[tid] += red2[tid + st]; }
        __syncthreads();
    }
    float m = red[0] * (1.f / D_);
    float v = red2[0] * (1.f / D_) - m * m;
    float rstd = rsqrtf(v + 1e-5f);

    for (int d = tid; d < D_; d += 256) {
        float fn = stm[d] + (rec[d] - m) * rstd * g[d] + be[d];
        finalf32[b * D_ + d] = fn;
        dout[b * D_ + d] = fn;
    }
}

// ---------------------------------------------------------------------------
// K4: fc1 GEMM  z1[b][j] = sum_k final[b][k]*fc1w[k][j], K-split by 64.
// ---------------------------------------------------------------------------
__global__ __launch_bounds__(256) void k_fc1(
    const float* __restrict__ finalf32, const float* __restrict__ fc1w,
    float* __restrict__ z1p)
{
    int kc = blockIdx.x;
    int t  = threadIdx.x;
    int k0 = kc * 64;
    const float2* W2 = (const float2*)fc1w;

    float a0[32], a1[32];
#pragma unroll
    for (int b = 0; b < 32; b++) { a0[b] = 0.f; a1[b] = 0.f; }

    for (int k = k0; k < k0 + 64; k++) {
        float2 wv = W2[k * (H1_ / 2) + t];
#pragma unroll
        for (int b = 0; b < 32; b++) {
            float a = finalf32[b * D_ + k];        // uniform -> s_load
            a0[b] = fmaf(a, wv.x, a0[b]);
            a1[b] = fmaf(a, wv.y, a1[b]);
        }
    }
    float* P = z1p + (size_t)kc * 32 * H1_;
#pragma unroll
    for (int b = 0; b < 32; b++) {
        P[b * H1_ + 2 * t]     = a0[b];
        P[b * H1_ + 2 * t + 1] = a1[b];
    }
}

// ---------------------------------------------------------------------------
// K5: MLP tail per batch row.
// ---------------------------------------------------------------------------
__global__ __launch_bounds__(256) void k_tail(
    const float* __restrict__ z1p,
    const float* __restrict__ fc1b,
    const float* __restrict__ ln1g, const float* __restrict__ ln1b,
    const float* __restrict__ fc2w, const float* __restrict__ fc2b,
    const float* __restrict__ ln2g, const float* __restrict__ ln2b,
    const float* __restrict__ fc3w, const float* __restrict__ fc3b,
    const float* __restrict__ lnog, const float* __restrict__ lnob,
    float* __restrict__ tanhout)
{
    __shared__ float sm[512];
    __shared__ float red[256], red2[256];
    __shared__ float h2s[256];
    int b = blockIdx.x, tid = threadIdx.x;

    for (int j = tid; j < H1_; j += 256) {
        float s = fc1b[j];
        for (int c = 0; c < 64; c++)
            s += z1p[((size_t)c * 32 + b) * H1_ + j];
        sm[j] = s;
    }
    __syncthreads();

    float s = 0.f, s2 = 0.f;
    for (int j = tid; j < H1_; j += 256) { float x = sm[j]; s += x; s2 += x * x; }
    red[tid] = s; red2[tid] = s2; __syncthreads();
    for (int st = 128; st > 0; st >>= 1) {
        if (tid < st) { red[tid] += red[tid + st]; red2[tid] += red2[tid + st]; }
        __syncthreads();
    }
    float m = red[0] * (1.f / H1_);
    float v = red2[0] * (1.f / H1_) - m * m;
    float rstd = rsqrtf(v + 1e-5f);
    __syncthreads();
    for (int j = tid; j < H1_; j += 256) {
        float h = (sm[j] - m) * rstd * ln1g[j] + ln1b[j];
        sm[j] = fmaxf(h, 0.f);
    }
    __syncthreads();

    float acc = fc2b[tid];
    for (int k = 0; k < H1_; k++)
        acc = fmaf(sm[k], fc2w[k * H2_ + tid], acc);
    red[tid] = acc; red2[tid] = acc * acc; __syncthreads();
    for (int st = 128; st > 0; st >>= 1) {
        if (tid < st) { red[tid] += red[tid + st]; red2[tid] += red2[tid + st]; }
        __syncthreads();
    }
    float m2 = red[0] * (1.f / H2_);
    float v2 = red2[0] * (1.f / H2_) - m2 * m2;
    float rstd2 = rsqrtf(v2 + 1e-5f);
    float h2 = fmaxf((acc - m2) * rstd2 * ln2g[tid] + ln2b[tid], 0.f);
    __syncthreads();
    h2s[tid] = h2; __syncthreads();

    int j  = tid & 63;
    int ks = tid >> 6;
    float p = 0.f;
    for (int kk = 0; kk < 64; kk++) {
        int k = ks * 64 + kk;
        p = fmaf(h2s[k], fc3w[k * U_ + j], p);
    }
    red[tid] = p; __syncthreads();
    if (tid < 64) {
        float x = red[tid] + red[tid + 64] + red[tid + 128] + red[tid + 192]
                + fc3b[tid];
        float ss = x, qq = x * x;
#pragma unroll
        for (int off = 32; off; off >>= 1) {
            ss += __shfl_xor(ss, off, 64);
            qq += __shfl_xor(qq, off, 64);
        }
        float m3 = ss * (1.f / U_);
        float v3 = qq * (1.f / U_) - m3 * m3;
        float to = tanhf((x - m3) * rsqrtf(v3 + 1e-5f) * lnog[tid] + lnob[tid]);
        tanhout[b * U_ + tid] = to;
    }
}

// ---------------------------------------------------------------------------
// K6: weight update + row L2 normalize via MFMA, TRANSPOSED tiles.
// Compute D[m=j][n=i] = sum_b Aout[b][j]*Astim[b][i]:
//   A-frag = OT[(j0+col)*32 + quad*8]  (varies per tile)
//   B-frag = ST[(i0+col)*32 + quad*8]  (constant per block)
// C layout: i = i0+col (lane), j = j0 + quad*4 + r -> r walks 4 CONSECUTIVE j
// => W read and output store are single float4 ops per lane (16B/lane).
// grid 512 = [mat(2)][i-tile(256)], block 512 thr = 8 waves; wave w owns
// j-tiles t*8+w (32 tiles).  v cached packed-bf16 in regs (static idx).
// ---------------------------------------------------------------------------
__global__ __launch_bounds__(512, 2) void k_update(
    const float* __restrict__ Wheb, const float* __restrict__ Wrec,
    const float* __restrict__ decay, const float* __restrict__ tanhout,
    const ushort_t* __restrict__ Tbuf, float* __restrict__ dout)
{
    __shared__ float ssl[8][16];
    int bx   = blockIdx.x;          // 512 = 2 mats x 256 i-tiles
    int mat  = bx >> 8;
    int i0   = (bx & 255) * 16;
    int tid  = threadIdx.x;
    int wave = tid >> 6, lane = tid & 63;
    int col  = lane & 15, quad = lane >> 4;

    // alpha per 64-wide j-group (lane index == group index)
    float al = 0.f;
#pragma unroll
    for (int b = 0; b < 32; b++) al += tanhout[b * U_ + lane];
    al *= (9.9f / 32.f);

    const ushort_t* Sp = Tbuf + mat * 131072;        // ST / PT  [i][b]
    const ushort_t* Op = Tbuf + (2 + mat) * 131072;  // OT / RT  [j][b]
    const float*    Wp = mat ? Wrec : Wheb;

    // B-frag constant across tiles: B[k=b][n=i] = ST[(i0+col)*32 + b]
    s16x8 bfr = *(const s16x8*)&Sp[(i0 + col) * 32 + quad * 8];

    float dc = 1.f - decay[i0 + col];    // per-lane row scale (i = i0+col)

    uint32_t vc[32][2];             // packed bf16 cache: 4 consecutive-j v's
    float ss = 0.f;                 // partial row-norm for row i0+col

#pragma unroll
    for (int t = 0; t < 32; t++) {
        int tile = t * 8 + wave;
        int j0   = tile * 16;
        float av = __shfl(al, tile >> 2, 64);    // alpha group = j0/64
        s16x8 af = *(const s16x8*)&Op[(j0 + col) * 32 + quad * 8];
        f32x4 u = (f32x4){0.f, 0.f, 0.f, 0.f};
        u = __builtin_amdgcn_mfma_f32_16x16x32_bf16(af, bfr, u, 0, 0, 0);
        // W[i0+col][j0 + quad*4 .. +3] as one float4
        const float4 w4 = *(const float4*)(Wp + (size_t)(i0 + col) * D_
                                           + j0 + quad * 4);
        float v0 = fmaf(av, u[0], w4.x) * dc;
        float v1 = fmaf(av, u[1], w4.y) * dc;
        float v2 = fmaf(av, u[2], w4.z) * dc;
        float v3 = fmaf(av, u[3], w4.w) * dc;
        ss = fmaf(v0, v0, ss);
        ss = fmaf(v1, v1, ss);
        ss = fmaf(v2, v2, ss);
        ss = fmaf(v3, v3, ss);
        vc[t][0] = pk2bf(v0, v1);
        vc[t][1] = pk2bf(v2, v3);
    }

    // reduce ss across the 4 quads sharing this col (lanes col+16q)
    ss += __shfl_xor(ss, 16, 64);
    ss += __shfl_xor(ss, 32, 64);
    if (quad == 0) ssl[wave][col] = ss;
    __syncthreads();
    float st = 0.f;
#pragma unroll
    for (int w = 0; w < 8; w++) st += ssl[w][col];
    float ri = 1.f / fmaxf(sqrtf(st), 1e-12f);

    float* O = dout + (size_t)(32 + mat * D_ + i0 + col) * D_;
#pragma unroll
    for (int t = 0; t < 32; t++) {
        int j0 = (t * 8 + wave) * 16 + quad * 4;
        float4 o;
        o.x = __uint_as_float(vc[t][0] << 16)         * ri;
        o.y = __uint_as_float(vc[t][0] & 0xffff0000u) * ri;
        o.z = __uint_as_float(vc[t][1] << 16)         * ri;
        o.w = __uint_as_float(vc[t][1] & 0xffff0000u) * ri;
        *(float4*)(O + j0) = o;
    }
}

// ---------------------------------------------------------------------------
extern "C" void kernel_launch(void* const* d_in, const int* in_sizes, int n_in,
                              void* d_out, int out_size, void* d_ws, size_t ws_size,
                              hipStream_t stream)
{
    const float* stim = (const float*)d_in[0];
    const float* prev = (const float*)d_in[1];
    const float* Wheb = (const float*)d_in[2];
    const float* Wrec = (const float*)d_in[3];
    const float* decay= (const float*)d_in[4];
    const float* lnrg = (const float*)d_in[5];
    const float* lnrb = (const float*)d_in[6];
    const float* fc1w = (const float*)d_in[7];
    const float* fc1b = (const float*)d_in[8];
    const float* ln1g = (const float*)d_in[9];
    const float* ln1b = (const float*)d_in[10];
    const float* fc2w = (const float*)d_in[11];
    const float* fc2b = (const float*)d_in[12];
    const float* ln2g = (const float*)d_in[13];
    const float* ln2b = (const float*)d_in[14];
    const float* fc3w = (const float*)d_in[15];
    const float* fc3b = (const float*)d_in[16];
    const float* lnog = (const float*)d_in[17];
    const float* lnob = (const float*)d_in[18];

    // Fixed-tail workspace: P_relu(1MB) Tbuf(1MB) P_final(512KB) z1p(4MB) tanh(8KB)
    const size_t FIXED = 1048576u + 1048576u + 524288u + 4194304u + 8192u; // 6823936
    // Slice count for K-split partials: 1 MB per slice, up to 16 (no atomics).
    int ns = 16;
    if (ws_size < FIXED + 16u * 1048576u) {
        size_t avail = (ws_size > FIXED) ? (ws_size - FIXED) / 1048576u : 1u;
        ns = (int)avail;
        if (ns < 1) ns = 1;
        if (ns > 16) ns = 16;
    }

    char* ws = (char*)d_ws;
    float*    P_sum   = (float*)(ws + 0);                 // ns MB  [ns][2][32][4096]
    char*     rest    = ws + (size_t)ns * 1048576u;
    float*    P_relu  = (float*)(rest + 0);               // 1 MB   [2][32][4096]
    ushort_t* P_tbuf  = (ushort_t*)(rest + 1048576);      // 1 MB   ST,PT,OT,RT (bf16)
    float*    P_final = (float*)(rest + 2097152);         // 512 KB [32][4096]
    float*    P_z1p   = (float*)(rest + 2621440);         // 4 MB   [64][32][512]
    float*    P_tanh  = (float*)(rest + 6815744);         // 8 KB   [32][64]

    float* out = (float*)d_out;

    if (ns < 16)  // atomic fallback needs zeroed partials
        hipMemsetAsync(P_sum, 0, (size_t)ns * 1048576u, stream);

    k_gemm_mfma<<<1024, 256, 0, stream>>>(stim, prev, Wheb, Wrec, P_sum, ns);
    k_reduce   <<<1024, 256, 0, stream>>>(P_sum, stim, prev, P_relu, P_tbuf, ns);
    k_final_ln <<<32,   256, 0, stream>>>(P_relu, lnrg, lnrb, out, P_final);
    k_fc1      <<<64,   256, 0, stream>>>(P_final, fc1w, P_z1p);
    k_tail     <<<32,   256, 0, stream>>>(P_z1p, fc1b, ln1g, ln1b, fc2w, fc2b,
                                          ln2g, ln2b, fc3w, fc3b, lnog, lnob, P_tanh);
    k_update   <<<512,  512, 0, stream>>>(Wheb, Wrec, decay, P_tanh, P_tbuf, out);
}

// Round 4
// 401.264 us; speedup vs baseline: 1.1937x; 1.0049x over previous
//
#include <hip/hip_runtime.h>
#include <stdint.h>

typedef unsigned short ushort_t;
typedef float f32x4 __attribute__((ext_vector_type(4)));
typedef short s16x8 __attribute__((ext_vector_type(8)));

#define B_  32
#define D_  4096
#define H1_ 512
#define H2_ 256
#define U_  64

#define KS_   16        // K-splits for forward GEMM
#define KCH_  256       // K per block (4096/16)
#define NT_   128       // N tile per block
#define APAD  264       // A_lds row stride (u16): 256 + 8 (16B aligned)
#define WPAD  70        // Wt_lds row stride (u16): 140B rows -> 4-way write conflict max

__device__ __forceinline__ float bf2f(ushort_t u) {
    return __uint_as_float(((uint32_t)u) << 16);
}
__device__ __forceinline__ ushort_t f2bfu(float f) {  // RNE float->bf16 bits
    uint32_t x = __float_as_uint(f);
    return (ushort_t)((x + 0x7fffu + ((x >> 16) & 1u)) >> 16);
}
__device__ __forceinline__ uint32_t pk2bf(float a, float b) {
    return ((uint32_t)f2bfu(a)) | (((uint32_t)f2bfu(b)) << 16);
}

// ---------------------------------------------------------------------------
// K1: forward GEMMs via MFMA 16x16x32 bf16, register-double-buffered W stage.
// C[b][n] = sum_k A[b][k] * W[k][n], A=[32 x 4096] fp32, W=[4096 x 4096] fp32.
// grid 1024: [gemm(2)][nblk(32)][kchunk(16)].  Block: 256 thr = 4 waves.
// Per kstep: pack prefetched regs -> LDS, then ISSUE next kstep's loads
// before the barrier so HBM latency hides under compute + barrier wait.
// ---------------------------------------------------------------------------
__global__ __launch_bounds__(256, 4) void k_gemm_mfma(
    const float* __restrict__ stim, const float* __restrict__ prev,
    const float* __restrict__ Wheb, const float* __restrict__ Wrec,
    float* __restrict__ Psum, int ns)
{
    __shared__ ushort_t Al[32 * APAD];     // 16.5 KB
    __shared__ ushort_t Wt[NT_ * WPAD];    // 17.5 KB

    int bx = blockIdx.x;
    int gemm  = bx >> 9;
    int rem   = bx & 511;
    int nblk  = rem >> 4;
    int chunk = rem & 15;
    const float* A = gemm ? prev : stim;
    const float* W = gemm ? Wrec : Wheb;
    int k0c = chunk * KCH_;
    int n0  = nblk * NT_;
    int tid = threadIdx.x, lane = tid & 63, wave = tid >> 6;
    int col = lane & 15, quad = lane >> 4;

    // ---- stage A [32][256] fp32 -> bf16 LDS via float4 (once per block)
#pragma unroll
    for (int p = 0; p < 8; p++) {
        int idx = p * 256 + tid;           // over [32][64] float4
        int b   = idx >> 6;
        int k4  = (idx & 63) * 4;
        float4 v = *(const float4*)(A + (size_t)b * D_ + k0c + k4);
        uint2 w; w.x = pk2bf(v.x, v.y); w.y = pk2bf(v.z, v.w);
        *(uint2*)&Al[b * APAD + k4] = w;
    }

    f32x4 acc[2][2];
#pragma unroll
    for (int mt = 0; mt < 2; mt++)
#pragma unroll
        for (int nt = 0; nt < 2; nt++)
            acc[mt][nt] = (f32x4){0.f, 0.f, 0.f, 0.f};

    int m = tid & 31;                      // n4 = m*4 (n within tile)
    int g = tid >> 5;                      // kpair group 0..7

    // ---- prologue: prefetch kstep 0 into registers
    float4 pr0[4], pr1[4];
    {
        const float* Wb = W + (size_t)k0c * D_ + n0 + m * 4;
#pragma unroll
        for (int i = 0; i < 4; i++) {
            int kp = g + 8 * i;
            pr0[i] = *(const float4*)(Wb + (size_t)(2 * kp) * D_);
            pr1[i] = *(const float4*)(Wb + (size_t)(2 * kp) * D_ + D_);
        }
    }

    // ---- K loop: 4 ksteps of 64, register double-buffered
    for (int ks = 0; ks < 4; ks++) {
        __syncthreads();                   // Wt free (prev compute done)
        // pack prefetched regs -> LDS (transposed)
#pragma unroll
        for (int i = 0; i < 4; i++) {
            int kp = g + 8 * i;
            *(uint32_t*)&Wt[(m * 4 + 0) * WPAD + 2 * kp] = pk2bf(pr0[i].x, pr1[i].x);
            *(uint32_t*)&Wt[(m * 4 + 1) * WPAD + 2 * kp] = pk2bf(pr0[i].y, pr1[i].y);
            *(uint32_t*)&Wt[(m * 4 + 2) * WPAD + 2 * kp] = pk2bf(pr0[i].z, pr1[i].z);
            *(uint32_t*)&Wt[(m * 4 + 3) * WPAD + 2 * kp] = pk2bf(pr0[i].w, pr1[i].w);
        }
        // issue NEXT kstep's loads now; they complete during compute+barriers
        if (ks < 3) {
            const float* Wb = W + (size_t)(k0c + (ks + 1) * 64) * D_ + n0 + m * 4;
#pragma unroll
            for (int i = 0; i < 4; i++) {
                int kp = g + 8 * i;
                pr0[i] = *(const float4*)(Wb + (size_t)(2 * kp) * D_);
                pr1[i] = *(const float4*)(Wb + (size_t)(2 * kp) * D_ + D_);
            }
        }
        __syncthreads();                   // Wt ready

#pragma unroll
        for (int kq = 0; kq < 2; kq++) {
            int kb = ks * 64 + kq * 32 + quad * 8;   // k in A_lds chunk
            int kw = kq * 32 + quad * 8;             // k in Wt row
            s16x8 af[2], bf[2];
            af[0] = *(const s16x8*)&Al[col * APAD + kb];
            af[1] = *(const s16x8*)&Al[(col + 16) * APAD + kb];
#pragma unroll
            for (int nt = 0; nt < 2; nt++)
                bf[nt] = *(const s16x8*)&Wt[(wave * 32 + nt * 16 + col) * WPAD + kw];
#pragma unroll
            for (int mt = 0; mt < 2; mt++)
#pragma unroll
                for (int nt = 0; nt < 2; nt++)
                    acc[mt][nt] = __builtin_amdgcn_mfma_f32_16x16x32_bf16(
                        af[mt], bf[nt], acc[mt][nt], 0, 0, 0);
        }
    }

    // ---- epilogue: write K-split partials to this chunk's slice
    int slice = chunk % ns;                // ns==16 -> slice==chunk (exclusive)
    float* P = Psum + ((size_t)slice * 2 + gemm) * 32 * D_;
    if (ns == 16) {
#pragma unroll
        for (int mt = 0; mt < 2; mt++)
#pragma unroll
            for (int nt = 0; nt < 2; nt++)
#pragma unroll
                for (int r = 0; r < 4; r++) {
                    int b = mt * 16 + quad * 4 + r;
                    int n = n0 + wave * 32 + nt * 16 + col;
                    P[(size_t)b * D_ + n] = acc[mt][nt][r];
                }
    } else {
#pragma unroll
        for (int mt = 0; mt < 2; mt++)
#pragma unroll
            for (int nt = 0; nt < 2; nt++)
#pragma unroll
                for (int r = 0; r < 4; r++) {
                    int b = mt * 16 + quad * 4 + r;
                    int n = n0 + wave * 32 + nt * 16 + col;
                    atomicAdd(&P[(size_t)b * D_ + n], acc[mt][nt][r]);
                }
    }
}

// ---------------------------------------------------------------------------
// K2: sum slices + relu -> P_relu + build bf16 transposed copies with
// COALESCED stores (LDS 32x32 tile transpose instead of 2B global scatter).
// grid 256 = [gemm(2)][dblk(128)]; block 256 thr covers [32 b][32 d].
//   Tbuf sections of 4096*32 u16: [0]=ST, [1]=PT, [2]=OT, [3]=RT
// ---------------------------------------------------------------------------
__global__ __launch_bounds__(256) void k_reduce(
    const float* __restrict__ Psum,
    const float* __restrict__ stim, const float* __restrict__ prev,
    float* __restrict__ P_relu, ushort_t* __restrict__ Tbuf, int ns)
{
    __shared__ ushort_t T0[32][33];   // [d][b] input transpose (pad 33)
    __shared__ ushort_t T1[32][33];   // [d][b] relu-out transpose
    int bx   = blockIdx.x;
    int gemm = bx >> 7;
    int d0   = (bx & 127) * 32;
    int tid  = threadIdx.x;
    int b    = tid >> 3;              // 0..31
    int dq   = (tid & 7) * 4;         // 0,4,..,28
    const float* In = gemm ? prev : stim;
    size_t base = (size_t)b * D_ + d0 + dq;

    float4 s = {0.f, 0.f, 0.f, 0.f};
    for (int sl = 0; sl < ns; sl++) {
        float4 p = *(const float4*)(Psum + ((size_t)(sl * 2 + gemm)) * 131072 + base);
        s.x += p.x; s.y += p.y; s.z += p.z; s.w += p.w;
    }
    s.x = fmaxf(s.x, 0.f); s.y = fmaxf(s.y, 0.f);
    s.z = fmaxf(s.z, 0.f); s.w = fmaxf(s.w, 0.f);
    *(float4*)(P_relu + (size_t)gemm * 131072 + base) = s;

    float4 iv = *(const float4*)(In + base);
    T1[dq + 0][b] = f2bfu(s.x);  T1[dq + 1][b] = f2bfu(s.y);
    T1[dq + 2][b] = f2bfu(s.z);  T1[dq + 3][b] = f2bfu(s.w);
    T0[dq + 0][b] = f2bfu(iv.x); T0[dq + 1][b] = f2bfu(iv.y);
    T0[dq + 2][b] = f2bfu(iv.z); T0[dq + 3][b] = f2bfu(iv.w);
    __syncthreads();

    // coalesced store: thread t -> row d=t>>3, bytes [ (t&7)*4 .. +3 ] u16
    int d  = tid >> 3;
    int i4 = (tid & 7) * 4;
    size_t toff = (size_t)(d0 + d) * 32 + i4;
    uint2 w0, w1;
    w0.x = ((uint32_t)T0[d][i4 + 0]) | (((uint32_t)T0[d][i4 + 1]) << 16);
    w0.y = ((uint32_t)T0[d][i4 + 2]) | (((uint32_t)T0[d][i4 + 3]) << 16);
    w1.x = ((uint32_t)T1[d][i4 + 0]) | (((uint32_t)T1[d][i4 + 1]) << 16);
    w1.y = ((uint32_t)T1[d][i4 + 2]) | (((uint32_t)T1[d][i4 + 3]) << 16);
    *(uint2*)(Tbuf + (size_t)gemm * 131072 + toff)       = w0;  // ST / PT
    *(uint2*)(Tbuf + (size_t)(2 + gemm) * 131072 + toff) = w1;  // OT / RT
}

// ---------------------------------------------------------------------------
// K3: rec_norm = LN(rec_out) per batch row; final = stim_out + rec_norm.
// float4 everywhere; writes only dout rows 0..31 (k_fc1 reads from there).
// ---------------------------------------------------------------------------
__global__ __launch_bounds__(256) void k_final_ln(
    const float* __restrict__ P_relu,
    const float* __restrict__ g, const float* __restrict__ be,
    float* __restrict__ dout)
{
    __shared__ float red[256], red2[256];
    int b = blockIdx.x, tid = threadIdx.x;
    const float* rec = P_relu + 131072 + b * D_;
    const float* stm = P_relu + b * D_;

    float s = 0.f, s2 = 0.f;
    for (int d = tid * 4; d < D_; d += 1024) {
        float4 x = *(const float4*)(rec + d);
        s  += x.x + x.y + x.z + x.w;
        s2 += x.x * x.x + x.y * x.y + x.z * x.z + x.w * x.w;
    }
    red[tid] = s; red2[tid] = s2; __syncthreads();
    for (int st = 128; st > 0; st >>= 1) {
        if (tid < st) { red[tid] += red[tid + st]; red2[tid] += red2[tid + st]; }
        __syncthreads();
    }
    float m = red[0] * (1.f / D_);
    float v = red2[0] * (1.f / D_) - m * m;
    float rstd = rsqrtf(v + 1e-5f);

    for (int d = tid * 4; d < D_; d += 1024) {
        float4 rv = *(const float4*)(rec + d);
        float4 sv = *(const float4*)(stm + d);
        float4 gv = *(const float4*)(g + d);
        float4 bv = *(const float4*)(be + d);
        float4 o;
        o.x = sv.x + (rv.x - m) * rstd * gv.x + bv.x;
        o.y = sv.y + (rv.y - m) * rstd * gv.y + bv.y;
        o.z = sv.z + (rv.z - m) * rstd * gv.z + bv.z;
        o.w = sv.w + (rv.w - m) * rstd * gv.w + bv.w;
        *(float4*)(dout + (size_t)b * D_ + d) = o;
    }
}

// ---------------------------------------------------------------------------
// K4: fc1 GEMM  z1[b][j] = sum_k final[b][k]*fc1w[k][j], K-split by 64.
// Reads final directly from dout rows 0..31.
// ---------------------------------------------------------------------------
__global__ __launch_bounds__(256) void k_fc1(
    const float* __restrict__ finalf32, const float* __restrict__ fc1w,
    float* __restrict__ z1p)
{
    int kc = blockIdx.x;
    int t  = threadIdx.x;
    int k0 = kc * 64;
    const float2* W2 = (const float2*)fc1w;

    float a0[32], a1[32];
#pragma unroll
    for (int b = 0; b < 32; b++) { a0[b] = 0.f; a1[b] = 0.f; }

    for (int k = k0; k < k0 + 64; k++) {
        float2 wv = W2[k * (H1_ / 2) + t];
#pragma unroll
        for (int b = 0; b < 32; b++) {
            float a = finalf32[b * D_ + k];        // uniform -> s_load
            a0[b] = fmaf(a, wv.x, a0[b]);
            a1[b] = fmaf(a, wv.y, a1[b]);
        }
    }
    float* P = z1p + (size_t)kc * 32 * H1_;
#pragma unroll
    for (int b = 0; b < 32; b++) {
        P[b * H1_ + 2 * t]     = a0[b];
        P[b * H1_ + 2 * t + 1] = a1[b];
    }
}

// ---------------------------------------------------------------------------
// K5: MLP tail per batch row.
// ---------------------------------------------------------------------------
__global__ __launch_bounds__(256) void k_tail(
    const float* __restrict__ z1p,
    const float* __restrict__ fc1b,
    const float* __restrict__ ln1g, const float* __restrict__ ln1b,
    const float* __restrict__ fc2w, const float* __restrict__ fc2b,
    const float* __restrict__ ln2g, const float* __restrict__ ln2b,
    const float* __restrict__ fc3w, const float* __restrict__ fc3b,
    const float* __restrict__ lnog, const float* __restrict__ lnob,
    float* __restrict__ tanhout)
{
    __shared__ float sm[512];
    __shared__ float red[256], red2[256];
    __shared__ float h2s[256];
    int b = blockIdx.x, tid = threadIdx.x;

    for (int j = tid; j < H1_; j += 256) {
        float s = fc1b[j];
        for (int c = 0; c < 64; c++)
            s += z1p[((size_t)c * 32 + b) * H1_ + j];
        sm[j] = s;
    }
    __syncthreads();

    float s = 0.f, s2 = 0.f;
    for (int j = tid; j < H1_; j += 256) { float x = sm[j]; s += x; s2 += x * x; }
    red[tid] = s; red2[tid] = s2; __syncthreads();
    for (int st = 128; st > 0; st >>= 1) {
        if (tid < st) { red[tid] += red[tid + st]; red2[tid] += red2[tid + st]; }
        __syncthreads();
    }
    float m = red[0] * (1.f / H1_);
    float v = red2[0] * (1.f / H1_) - m * m;
    float rstd = rsqrtf(v + 1e-5f);
    __syncthreads();
    for (int j = tid; j < H1_; j += 256) {
        float h = (sm[j] - m) * rstd * ln1g[j] + ln1b[j];
        sm[j] = fmaxf(h, 0.f);
    }
    __syncthreads();

    float acc = fc2b[tid];
    for (int k = 0; k < H1_; k++)
        acc = fmaf(sm[k], fc2w[k * H2_ + tid], acc);
    red[tid] = acc; red2[tid] = acc * acc; __syncthreads();
    for (int st = 128; st > 0; st >>= 1) {
        if (tid < st) { red[tid] += red[tid + st]; red2[tid] += red2[tid + st]; }
        __syncthreads();
    }
    float m2 = red[0] * (1.f / H2_);
    float v2 = red2[0] * (1.f / H2_) - m2 * m2;
    float rstd2 = rsqrtf(v2 + 1e-5f);
    float h2 = fmaxf((acc - m2) * rstd2 * ln2g[tid] + ln2b[tid], 0.f);
    __syncthreads();
    h2s[tid] = h2; __syncthreads();

    int j  = tid & 63;
    int ks = tid >> 6;
    float p = 0.f;
    for (int kk = 0; kk < 64; kk++) {
        int k = ks * 64 + kk;
        p = fmaf(h2s[k], fc3w[k * U_ + j], p);
    }
    red[tid] = p; __syncthreads();
    if (tid < 64) {
        float x = red[tid] + red[tid + 64] + red[tid + 128] + red[tid + 192]
                + fc3b[tid];
        float ss = x, qq = x * x;
#pragma unroll
        for (int off = 32; off; off >>= 1) {
            ss += __shfl_xor(ss, off, 64);
            qq += __shfl_xor(qq, off, 64);
        }
        float m3 = ss * (1.f / U_);
        float v3 = qq * (1.f / U_) - m3 * m3;
        float to = tanhf((x - m3) * rsqrtf(v3 + 1e-5f) * lnog[tid] + lnob[tid]);
        tanhout[b * U_ + tid] = to;
    }
}

// ---------------------------------------------------------------------------
// K6: weight update + row L2 normalize via MFMA, transposed tiles (as R2).
// ---------------------------------------------------------------------------
__global__ __launch_bounds__(512, 2) void k_update(
    const float* __restrict__ Wheb, const float* __restrict__ Wrec,
    const float* __restrict__ decay, const float* __restrict__ tanhout,
    const ushort_t* __restrict__ Tbuf, float* __restrict__ dout)
{
    __shared__ float ssl[8][16];
    int bx   = blockIdx.x;          // 512 = 2 mats x 256 i-tiles
    int mat  = bx >> 8;
    int i0   = (bx & 255) * 16;
    int tid  = threadIdx.x;
    int wave = tid >> 6, lane = tid & 63;
    int col  = lane & 15, quad = lane >> 4;

    // alpha per 64-wide j-group (lane index == group index)
    float al = 0.f;
#pragma unroll
    for (int b = 0; b < 32; b++) al += tanhout[b * U_ + lane];
    al *= (9.9f / 32.f);

    const ushort_t* Sp = Tbuf + mat * 131072;        // ST / PT  [i][b]
    const ushort_t* Op = Tbuf + (2 + mat) * 131072;  // OT / RT  [j][b]
    const float*    Wp = mat ? Wrec : Wheb;

    // B-frag constant across tiles: B[k=b][n=i] = ST[(i0+col)*32 + b]
    s16x8 bfr = *(const s16x8*)&Sp[(i0 + col) * 32 + quad * 8];

    float dc = 1.f - decay[i0 + col];    // per-lane row scale (i = i0+col)

    uint32_t vc[32][2];             // packed bf16 cache: 4 consecutive-j v's
    float ss = 0.f;                 // partial row-norm for row i0+col

#pragma unroll
    for (int t = 0; t < 32; t++) {
        int tile = t * 8 + wave;
        int j0   = tile * 16;
        float av = __shfl(al, tile >> 2, 64);    // alpha group = j0/64
        s16x8 af = *(const s16x8*)&Op[(j0 + col) * 32 + quad * 8];
        f32x4 u = (f32x4){0.f, 0.f, 0.f, 0.f};
        u = __builtin_amdgcn_mfma_f32_16x16x32_bf16(af, bfr, u, 0, 0, 0);
        const float4 w4 = *(const float4*)(Wp + (size_t)(i0 + col) * D_
                                           + j0 + quad * 4);
        float v0 = fmaf(av, u[0], w4.x) * dc;
        float v1 = fmaf(av, u[1], w4.y) * dc;
        float v2 = fmaf(av, u[2], w4.z) * dc;
        float v3 = fmaf(av, u[3], w4.w) * dc;
        ss = fmaf(v0, v0, ss);
        ss = fmaf(v1, v1, ss);
        ss = fmaf(v2, v2, ss);
        ss = fmaf(v3, v3, ss);
        vc[t][0] = pk2bf(v0, v1);
        vc[t][1] = pk2bf(v2, v3);
    }

    // reduce ss across the 4 quads sharing this col (lanes col+16q)
    ss += __shfl_xor(ss, 16, 64);
    ss += __shfl_xor(ss, 32, 64);
    if (quad == 0) ssl[wave][col] = ss;
    __syncthreads();
    float st = 0.f;
#pragma unroll
    for (int w = 0; w < 8; w++) st += ssl[w][col];
    float ri = 1.f / fmaxf(sqrtf(st), 1e-12f);

    float* O = dout + (size_t)(32 + mat * D_ + i0 + col) * D_;
#pragma unroll
    for (int t = 0; t < 32; t++) {
        int j0 = (t * 8 + wave) * 16 + quad * 4;
        float4 o;
        o.x = __uint_as_float(vc[t][0] << 16)         * ri;
        o.y = __uint_as_float(vc[t][0] & 0xffff0000u) * ri;
        o.z = __uint_as_float(vc[t][1] << 16)         * ri;
        o.w = __uint_as_float(vc[t][1] & 0xffff0000u) * ri;
        *(float4*)(O + j0) = o;
    }
}

// ---------------------------------------------------------------------------
extern "C" void kernel_launch(void* const* d_in, const int* in_sizes, int n_in,
                              void* d_out, int out_size, void* d_ws, size_t ws_size,
                              hipStream_t stream)
{
    const float* stim = (const float*)d_in[0];
    const float* prev = (const float*)d_in[1];
    const float* Wheb = (const float*)d_in[2];
    const float* Wrec = (const float*)d_in[3];
    const float* decay= (const float*)d_in[4];
    const float* lnrg = (const float*)d_in[5];
    const float* lnrb = (const float*)d_in[6];
    const float* fc1w = (const float*)d_in[7];
    const float* fc1b = (const float*)d_in[8];
    const float* ln1g = (const float*)d_in[9];
    const float* ln1b = (const float*)d_in[10];
    const float* fc2w = (const float*)d_in[11];
    const float* fc2b = (const float*)d_in[12];
    const float* ln2g = (const float*)d_in[13];
    const float* ln2b = (const float*)d_in[14];
    const float* fc3w = (const float*)d_in[15];
    const float* fc3b = (const float*)d_in[16];
    const float* lnog = (const float*)d_in[17];
    const float* lnob = (const float*)d_in[18];

    // Fixed-tail workspace: P_relu(1MB) Tbuf(1MB) pad(512KB) z1p(4MB) tanh(8KB)
    const size_t FIXED = 1048576u + 1048576u + 524288u + 4194304u + 8192u;
    int ns = 16;
    if (ws_size < FIXED + 16u * 1048576u) {
        size_t avail = (ws_size > FIXED) ? (ws_size - FIXED) / 1048576u : 1u;
        ns = (int)avail;
        if (ns < 1) ns = 1;
        if (ns > 16) ns = 16;
    }

    char* ws = (char*)d_ws;
    float*    P_sum   = (float*)(ws + 0);                 // ns MB  [ns][2][32][4096]
    char*     rest    = ws + (size_t)ns * 1048576u;
    float*    P_relu  = (float*)(rest + 0);               // 1 MB   [2][32][4096]
    ushort_t* P_tbuf  = (ushort_t*)(rest + 1048576);      // 1 MB   ST,PT,OT,RT (bf16)
    float*    P_z1p   = (float*)(rest + 2621440);         // 4 MB   [64][32][512]
    float*    P_tanh  = (float*)(rest + 6815744);         // 8 KB   [32][64]

    float* out = (float*)d_out;

    if (ns < 16)  // atomic fallback needs zeroed partials
        hipMemsetAsync(P_sum, 0, (size_t)ns * 1048576u, stream);

    k_gemm_mfma<<<1024, 256, 0, stream>>>(stim, prev, Wheb, Wrec, P_sum, ns);
    k_reduce   <<<256,  256, 0, stream>>>(P_sum, stim, prev, P_relu, P_tbuf, ns);
    k_final_ln <<<32,   256, 0, stream>>>(P_relu, lnrg, lnrb, out);
    k_fc1      <<<64,   256, 0, stream>>>(out, fc1w, P_z1p);
    k_tail     <<<32,   256, 0, stream>>>(P_z1p, fc1b, ln1g, ln1b, fc2w, fc2b,
                                          ln2g, ln2b, fc3w, fc3b, lnog, lnob, P_tanh);
    k_update   <<<512,  512, 0, stream>>>(Wheb, Wrec, decay, P_tanh, P_tbuf, out);
}

// Round 6
// 393.125 us; speedup vs baseline: 1.2184x; 1.0207x over previous
//
#include <hip/hip_runtime.h>
#include <stdint.h>

typedef unsigned short ushort_t;
typedef float f32x4 __attribute__((ext_vector_type(4)));
typedef short s16x8 __attribute__((ext_vector_type(8)));

#define B_  32
#define D_  4096
#define H1_ 512
#define H2_ 256
#define U_  64

#define KS_   16        // K-splits for forward GEMM
#define KCH_  256       // K per block (4096/16)
#define NT_   128       // N tile per block
#define APAD  264       // A_lds row stride (u16): 256 + 8 (16B aligned)
#define WPAD  70        // Wt_lds row stride (u16): 140B rows -> 4-way write conflict max

__device__ __forceinline__ float bf2f(ushort_t u) {
    return __uint_as_float(((uint32_t)u) << 16);
}
__device__ __forceinline__ ushort_t f2bfu(float f) {  // RNE float->bf16 bits
    uint32_t x = __float_as_uint(f);
    return (ushort_t)((x + 0x7fffu + ((x >> 16) & 1u)) >> 16);
}
__device__ __forceinline__ uint32_t pk2bf(float a, float b) {
    return ((uint32_t)f2bfu(a)) | (((uint32_t)f2bfu(b)) << 16);
}

// ---------------------------------------------------------------------------
// K1: forward GEMMs via MFMA 16x16x32 bf16, register-double-buffered W stage.
// C[b][n] = sum_k A[b][k] * W[k][n], A=[32 x 4096] fp32, W=[4096 x 4096] fp32.
// grid 1024: [gemm(2)][nblk(32)][kchunk(16)].  Block: 256 thr = 4 waves.
// Per kstep: pack prefetched regs -> LDS, then ISSUE next kstep's loads
// before the barrier so HBM latency hides under compute + barrier wait.
// ---------------------------------------------------------------------------
__global__ __launch_bounds__(256, 4) void k_gemm_mfma(
    const float* __restrict__ stim, const float* __restrict__ prev,
    const float* __restrict__ Wheb, const float* __restrict__ Wrec,
    float* __restrict__ Psum, int ns)
{
    __shared__ ushort_t Al[32 * APAD];     // 16.5 KB
    __shared__ ushort_t Wt[NT_ * WPAD];    // 17.5 KB

    int bx = blockIdx.x;
    int gemm  = bx >> 9;
    int rem   = bx & 511;
    int nblk  = rem >> 4;
    int chunk = rem & 15;
    const float* A = gemm ? prev : stim;
    const float* W = gemm ? Wrec : Wheb;
    int k0c = chunk * KCH_;
    int n0  = nblk * NT_;
    int tid = threadIdx.x, lane = tid & 63, wave = tid >> 6;
    int col = lane & 15, quad = lane >> 4;

    // ---- stage A [32][256] fp32 -> bf16 LDS via float4 (once per block)
#pragma unroll
    for (int p = 0; p < 8; p++) {
        int idx = p * 256 + tid;           // over [32][64] float4
        int b   = idx >> 6;
        int k4  = (idx & 63) * 4;
        float4 v = *(const float4*)(A + (size_t)b * D_ + k0c + k4);
        uint2 w; w.x = pk2bf(v.x, v.y); w.y = pk2bf(v.z, v.w);
        *(uint2*)&Al[b * APAD + k4] = w;
    }

    f32x4 acc[2][2];
#pragma unroll
    for (int mt = 0; mt < 2; mt++)
#pragma unroll
        for (int nt = 0; nt < 2; nt++)
            acc[mt][nt] = (f32x4){0.f, 0.f, 0.f, 0.f};

    int m = tid & 31;                      // n4 = m*4 (n within tile)
    int g = tid >> 5;                      // kpair group 0..7

    // ---- prologue: prefetch kstep 0 into registers
    float4 pr0[4], pr1[4];
    {
        const float* Wb = W + (size_t)k0c * D_ + n0 + m * 4;
#pragma unroll
        for (int i = 0; i < 4; i++) {
            int kp = g + 8 * i;
            pr0[i] = *(const float4*)(Wb + (size_t)(2 * kp) * D_);
            pr1[i] = *(const float4*)(Wb + (size_t)(2 * kp) * D_ + D_);
        }
    }

    // ---- K loop: 4 ksteps of 64, register double-buffered
    for (int ks = 0; ks < 4; ks++) {
        __syncthreads();                   // Wt free (prev compute done)
        // pack prefetched regs -> LDS (transposed)
#pragma unroll
        for (int i = 0; i < 4; i++) {
            int kp = g + 8 * i;
            *(uint32_t*)&Wt[(m * 4 + 0) * WPAD + 2 * kp] = pk2bf(pr0[i].x, pr1[i].x);
            *(uint32_t*)&Wt[(m * 4 + 1) * WPAD + 2 * kp] = pk2bf(pr0[i].y, pr1[i].y);
            *(uint32_t*)&Wt[(m * 4 + 2) * WPAD + 2 * kp] = pk2bf(pr0[i].z, pr1[i].z);
            *(uint32_t*)&Wt[(m * 4 + 3) * WPAD + 2 * kp] = pk2bf(pr0[i].w, pr1[i].w);
        }
        // issue NEXT kstep's loads now; they complete during compute+barriers
        if (ks < 3) {
            const float* Wb = W + (size_t)(k0c + (ks + 1) * 64) * D_ + n0 + m * 4;
#pragma unroll
            for (int i = 0; i < 4; i++) {
                int kp = g + 8 * i;
                pr0[i] = *(const float4*)(Wb + (size_t)(2 * kp) * D_);
                pr1[i] = *(const float4*)(Wb + (size_t)(2 * kp) * D_ + D_);
            }
        }
        __syncthreads();                   // Wt ready

#pragma unroll
        for (int kq = 0; kq < 2; kq++) {
            int kb = ks * 64 + kq * 32 + quad * 8;   // k in A_lds chunk
            int kw = kq * 32 + quad * 8;             // k in Wt row
            s16x8 af[2], bf[2];
            af[0] = *(const s16x8*)&Al[col * APAD + kb];
            af[1] = *(const s16x8*)&Al[(col + 16) * APAD + kb];
#pragma unroll
            for (int nt = 0; nt < 2; nt++)
                bf[nt] = *(const s16x8*)&Wt[(wave * 32 + nt * 16 + col) * WPAD + kw];
#pragma unroll
            for (int mt = 0; mt < 2; mt++)
#pragma unroll
                for (int nt = 0; nt < 2; nt++)
                    acc[mt][nt] = __builtin_amdgcn_mfma_f32_16x16x32_bf16(
                        af[mt], bf[nt], acc[mt][nt], 0, 0, 0);
        }
    }

    // ---- epilogue: write K-split partials to this chunk's slice
    int slice = chunk % ns;                // ns==16 -> slice==chunk (exclusive)
    float* P = Psum + ((size_t)slice * 2 + gemm) * 32 * D_;
    if (ns == 16) {
#pragma unroll
        for (int mt = 0; mt < 2; mt++)
#pragma unroll
            for (int nt = 0; nt < 2; nt++)
#pragma unroll
                for (int r = 0; r < 4; r++) {
                    int b = mt * 16 + quad * 4 + r;
                    int n = n0 + wave * 32 + nt * 16 + col;
                    P[(size_t)b * D_ + n] = acc[mt][nt][r];
                }
    } else {
#pragma unroll
        for (int mt = 0; mt < 2; mt++)
#pragma unroll
            for (int nt = 0; nt < 2; nt++)
#pragma unroll
                for (int r = 0; r < 4; r++) {
                    int b = mt * 16 + quad * 4 + r;
                    int n = n0 + wave * 32 + nt * 16 + col;
                    atomicAdd(&P[(size_t)b * D_ + n], acc[mt][nt][r]);
                }
    }
}

// ---------------------------------------------------------------------------
// K2: sum slices + relu -> P_relu + build bf16 transposed copies with
// COALESCED stores (LDS 32x32 tile transpose instead of 2B global scatter).
// grid 256 = [gemm(2)][dblk(128)]; block 256 thr covers [32 b][32 d].
//   Tbuf sections of 4096*32 u16: [0]=ST, [1]=PT, [2]=OT, [3]=RT
// ---------------------------------------------------------------------------
__global__ __launch_bounds__(256) void k_reduce(
    const float* __restrict__ Psum,
    const float* __restrict__ stim, const float* __restrict__ prev,
    float* __restrict__ P_relu, ushort_t* __restrict__ Tbuf, int ns)
{
    __shared__ ushort_t T0[32][33];   // [d][b] input transpose (pad 33)
    __shared__ ushort_t T1[32][33];   // [d][b] relu-out transpose
    int bx   = blockIdx.x;
    int gemm = bx >> 7;
    int d0   = (bx & 127) * 32;
    int tid  = threadIdx.x;
    int b    = tid >> 3;              // 0..31
    int dq   = (tid & 7) * 4;         // 0,4,..,28
    const float* In = gemm ? prev : stim;
    size_t base = (size_t)b * D_ + d0 + dq;

    float4 s = {0.f, 0.f, 0.f, 0.f};
    for (int sl = 0; sl < ns; sl++) {
        float4 p = *(const float4*)(Psum + ((size_t)(sl * 2 + gemm)) * 131072 + base);
        s.x += p.x; s.y += p.y; s.z += p.z; s.w += p.w;
    }
    s.x = fmaxf(s.x, 0.f); s.y = fmaxf(s.y, 0.f);
    s.z = fmaxf(s.z, 0.f); s.w = fmaxf(s.w, 0.f);
    *(float4*)(P_relu + (size_t)gemm * 131072 + base) = s;

    float4 iv = *(const float4*)(In + base);
    T1[dq + 0][b] = f2bfu(s.x);  T1[dq + 1][b] = f2bfu(s.y);
    T1[dq + 2][b] = f2bfu(s.z);  T1[dq + 3][b] = f2bfu(s.w);
    T0[dq + 0][b] = f2bfu(iv.x); T0[dq + 1][b] = f2bfu(iv.y);
    T0[dq + 2][b] = f2bfu(iv.z); T0[dq + 3][b] = f2bfu(iv.w);
    __syncthreads();

    // coalesced store: thread t -> row d=t>>3, bytes [ (t&7)*4 .. +3 ] u16
    int d  = tid >> 3;
    int i4 = (tid & 7) * 4;
    size_t toff = (size_t)(d0 + d) * 32 + i4;
    uint2 w0, w1;
    w0.x = ((uint32_t)T0[d][i4 + 0]) | (((uint32_t)T0[d][i4 + 1]) << 16);
    w0.y = ((uint32_t)T0[d][i4 + 2]) | (((uint32_t)T0[d][i4 + 3]) << 16);
    w1.x = ((uint32_t)T1[d][i4 + 0]) | (((uint32_t)T1[d][i4 + 1]) << 16);
    w1.y = ((uint32_t)T1[d][i4 + 2]) | (((uint32_t)T1[d][i4 + 3]) << 16);
    *(uint2*)(Tbuf + (size_t)gemm * 131072 + toff)       = w0;  // ST / PT
    *(uint2*)(Tbuf + (size_t)(2 + gemm) * 131072 + toff) = w1;  // OT / RT
}

// ---------------------------------------------------------------------------
// K3: rec_norm = LN(rec_out) per batch row; final = stim_out + rec_norm.
// float4 everywhere; writes only dout rows 0..31 (k_fc1 reads from there).
// ---------------------------------------------------------------------------
__global__ __launch_bounds__(256) void k_final_ln(
    const float* __restrict__ P_relu,
    const float* __restrict__ g, const float* __restrict__ be,
    float* __restrict__ dout)
{
    __shared__ float red[256], red2[256];
    int b = blockIdx.x, tid = threadIdx.x;
    const float* rec = P_relu + 131072 + b * D_;
    const float* stm = P_relu + b * D_;

    float s = 0.f, s2 = 0.f;
    for (int d = tid * 4; d < D_; d += 1024) {
        float4 x = *(const float4*)(rec + d);
        s  += x.x + x.y + x.z + x.w;
        s2 += x.x * x.x + x.y * x.y + x.z * x.z + x.w * x.w;
    }
    red[tid] = s; red2[tid] = s2; __syncthreads();
    for (int st = 128; st > 0; st >>= 1) {
        if (tid < st) { red[tid] += red[tid + st]; red2[tid] += red2[tid + st]; }
        __syncthreads();
    }
    float m = red[0] * (1.f / D_);
    float v = red2[0] * (1.f / D_) - m * m;
    float rstd = rsqrtf(v + 1e-5f);

    for (int d = tid * 4; d < D_; d += 1024) {
        float4 rv = *(const float4*)(rec + d);
        float4 sv = *(const float4*)(stm + d);
        float4 gv = *(const float4*)(g + d);
        float4 bv = *(const float4*)(be + d);
        float4 o;
        o.x = sv.x + (rv.x - m) * rstd * gv.x + bv.x;
        o.y = sv.y + (rv.y - m) * rstd * gv.y + bv.y;
        o.z = sv.z + (rv.z - m) * rstd * gv.z + bv.z;
        o.w = sv.w + (rv.w - m) * rstd * gv.w + bv.w;
        *(float4*)(dout + (size_t)b * D_ + d) = o;
    }
}

// ---------------------------------------------------------------------------
// K4: fc1 GEMM  z1[b][j] = sum_k final[b][k]*fc1w[k][j], K-split by 64.
// Reads final directly from dout rows 0..31.
// ---------------------------------------------------------------------------
__global__ __launch_bounds__(256) void k_fc1(
    const float* __restrict__ finalf32, const float* __restrict__ fc1w,
    float* __restrict__ z1p)
{
    int kc = blockIdx.x;
    int t  = threadIdx.x;
    int k0 = kc * 64;
    const float2* W2 = (const float2*)fc1w;

    float a0[32], a1[32];
#pragma unroll
    for (int b = 0; b < 32; b++) { a0[b] = 0.f; a1[b] = 0.f; }

    for (int k = k0; k < k0 + 64; k++) {
        float2 wv = W2[k * (H1_ / 2) + t];
#pragma unroll
        for (int b = 0; b < 32; b++) {
            float a = finalf32[b * D_ + k];        // uniform -> s_load
            a0[b] = fmaf(a, wv.x, a0[b]);
            a1[b] = fmaf(a, wv.y, a1[b]);
        }
    }
    float* P = z1p + (size_t)kc * 32 * H1_;
#pragma unroll
    for (int b = 0; b < 32; b++) {
        P[b * H1_ + 2 * t]     = a0[b];
        P[b * H1_ + 2 * t + 1] = a1[b];
    }
}

// ---------------------------------------------------------------------------
// K5: MLP tail per batch row.  z1p reduction via float2 (contiguous j pair).
// ---------------------------------------------------------------------------
__global__ __launch_bounds__(256) void k_tail(
    const float* __restrict__ z1p,
    const float* __restrict__ fc1b,
    const float* __restrict__ ln1g, const float* __restrict__ ln1b,
    const float* __restrict__ fc2w, const float* __restrict__ fc2b,
    const float* __restrict__ ln2g, const float* __restrict__ ln2b,
    const float* __restrict__ fc3w, const float* __restrict__ fc3b,
    const float* __restrict__ lnog, const float* __restrict__ lnob,
    float* __restrict__ tanhout)
{
    __shared__ float sm[512];
    __shared__ float red[256], red2[256];
    __shared__ float h2s[256];
    int b = blockIdx.x, tid = threadIdx.x;

    {   // each thread owns j = 2*tid, 2*tid+1  (512 = 256*2 exactly)
        int j = tid * 2;
        float2 s = *(const float2*)(fc1b + j);
        for (int c = 0; c < 64; c++) {
            float2 v = *(const float2*)(z1p + ((size_t)c * 32 + b) * H1_ + j);
            s.x += v.x; s.y += v.y;
        }
        sm[j] = s.x; sm[j + 1] = s.y;
    }
    __syncthreads();

    float s = 0.f, s2 = 0.f;
    for (int j = tid; j < H1_; j += 256) { float x = sm[j]; s += x; s2 += x * x; }
    red[tid] = s; red2[tid] = s2; __syncthreads();
    for (int st = 128; st > 0; st >>= 1) {
        if (tid < st) { red[tid] += red[tid + st]; red2[tid] += red2[tid + st]; }
        __syncthreads();
    }
    float m = red[0] * (1.f / H1_);
    float v = red2[0] * (1.f / H1_) - m * m;
    float rstd = rsqrtf(v + 1e-5f);
    __syncthreads();
    for (int j = tid; j < H1_; j += 256) {
        float h = (sm[j] - m) * rstd * ln1g[j] + ln1b[j];
        sm[j] = fmaxf(h, 0.f);
    }
    __syncthreads();

    float acc = fc2b[tid];
    for (int k = 0; k < H1_; k++)
        acc = fmaf(sm[k], fc2w[k * H2_ + tid], acc);
    red[tid] = acc; red2[tid] = acc * acc; __syncthreads();
    for (int st = 128; st > 0; st >>= 1) {
        if (tid < st) { red[tid] += red[tid + st]; red2[tid] += red2[tid + st]; }
        __syncthreads();
    }
    float m2 = red[0] * (1.f / H2_);
    float v2 = red2[0] * (1.f / H2_) - m2 * m2;
    float rstd2 = rsqrtf(v2 + 1e-5f);
    float h2 = fmaxf((acc - m2) * rstd2 * ln2g[tid] + ln2b[tid], 0.f);
    __syncthreads();
    h2s[tid] = h2; __syncthreads();

    int j  = tid & 63;
    int ks = tid >> 6;
    float p = 0.f;
    for (int kk = 0; kk < 64; kk++) {
        int k = ks * 64 + kk;
        p = fmaf(h2s[k], fc3w[k * U_ + j], p);
    }
    red[tid] = p; __syncthreads();
    if (tid < 64) {
        float x = red[tid] + red[tid + 64] + red[tid + 128] + red[tid + 192]
                + fc3b[tid];
        float ss = x, qq = x * x;
#pragma unroll
        for (int off = 32; off; off >>= 1) {
            ss += __shfl_xor(ss, off, 64);
            qq += __shfl_xor(qq, off, 64);
        }
        float m3 = ss * (1.f / U_);
        float v3 = qq * (1.f / U_) - m3 * m3;
        float to = tanhf((x - m3) * rsqrtf(v3 + 1e-5f) * lnog[tid] + lnob[tid]);
        tanhout[b * U_ + tid] = to;
    }
}

// ---------------------------------------------------------------------------
// K6: weight update + row L2 normalize via MFMA, transposed tiles.
// ---------------------------------------------------------------------------
__global__ __launch_bounds__(512, 2) void k_update(
    const float* __restrict__ Wheb, const float* __restrict__ Wrec,
    const float* __restrict__ decay, const float* __restrict__ tanhout,
    const ushort_t* __restrict__ Tbuf, float* __restrict__ dout)
{
    __shared__ float ssl[8][16];
    int bx   = blockIdx.x;          // 512 = 2 mats x 256 i-tiles
    int mat  = bx >> 8;
    int i0   = (bx & 255) * 16;
    int tid  = threadIdx.x;
    int wave = tid >> 6, lane = tid & 63;
    int col  = lane & 15, quad = lane >> 4;

    // alpha per 64-wide j-group (lane index == group index)
    float al = 0.f;
#pragma unroll
    for (int b = 0; b < 32; b++) al += tanhout[b * U_ + lane];
    al *= (9.9f / 32.f);

    const ushort_t* Sp = Tbuf + mat * 131072;        // ST / PT  [i][b]
    const ushort_t* Op = Tbuf + (2 + mat) * 131072;  // OT / RT  [j][b]
    const float*    Wp = mat ? Wrec : Wheb;

    // B-frag constant across tiles: B[k=b][n=i] = ST[(i0+col)*32 + b]
    s16x8 bfr = *(const s16x8*)&Sp[(i0 + col) * 32 + quad * 8];

    float dc = 1.f - decay[i0 + col];    // per-lane row scale (i = i0+col)

    uint32_t vc[32][2];             // packed bf16 cache: 4 consecutive-j v's
    float ss = 0.f;                 // partial row-norm for row i0+col

#pragma unroll
    for (int t = 0; t < 32; t++) {
        int tile = t * 8 + wave;
        int j0   = tile * 16;
        float av = __shfl(al, tile >> 2, 64);    // alpha group = j0/64
        s16x8 af = *(const s16x8*)&Op[(j0 + col) * 32 + quad * 8];
        f32x4 u = (f32x4){0.f, 0.f, 0.f, 0.f};
        u = __builtin_amdgcn_mfma_f32_16x16x32_bf16(af, bfr, u, 0, 0, 0);
        const float4 w4 = *(const float4*)(Wp + (size_t)(i0 + col) * D_
                                           + j0 + quad * 4);
        float v0 = fmaf(av, u[0], w4.x) * dc;
        float v1 = fmaf(av, u[1], w4.y) * dc;
        float v2 = fmaf(av, u[2], w4.z) * dc;
        float v3 = fmaf(av, u[3], w4.w) * dc;
        ss = fmaf(v0, v0, ss);
        ss = fmaf(v1, v1, ss);
        ss = fmaf(v2, v2, ss);
        ss = fmaf(v3, v3, ss);
        vc[t][0] = pk2bf(v0, v1);
        vc[t][1] = pk2bf(v2, v3);
    }

    // reduce ss across the 4 quads sharing this col (lanes col+16q)
    ss += __shfl_xor(ss, 16, 64);
    ss += __shfl_xor(ss, 32, 64);
    if (quad == 0) ssl[wave][col] = ss;
    __syncthreads();
    float st = 0.f;
#pragma unroll
    for (int w = 0; w < 8; w++) st += ssl[w][col];
    float ri = 1.f / fmaxf(sqrtf(st), 1e-12f);

    float* O = dout + (size_t)(32 + mat * D_ + i0 + col) * D_;
#pragma unroll
    for (int t = 0; t < 32; t++) {
        int j0 = (t * 8 + wave) * 16 + quad * 4;
        float4 o;
        o.x = __uint_as_float(vc[t][0] << 16)         * ri;
        o.y = __uint_as_float(vc[t][0] & 0xffff0000u) * ri;
        o.z = __uint_as_float(vc[t][1] << 16)         * ri;
        o.w = __uint_as_float(vc[t][1] & 0xffff0000u) * ri;
        *(float4*)(O + j0) = o;
    }
}

// ---------------------------------------------------------------------------
extern "C" void kernel_launch(void* const* d_in, const int* in_sizes, int n_in,
                              void* d_out, int out_size, void* d_ws, size_t ws_size,
                              hipStream_t stream)
{
    const float* stim = (const float*)d_in[0];
    const float* prev = (const float*)d_in[1];
    const float* Wheb = (const float*)d_in[2];
    const float* Wrec = (const float*)d_in[3];
    const float* decay= (const float*)d_in[4];
    const float* lnrg = (const float*)d_in[5];
    const float* lnrb = (const float*)d_in[6];
    const float* fc1w = (const float*)d_in[7];
    const float* fc1b = (const float*)d_in[8];
    const float* ln1g = (const float*)d_in[9];
    const float* ln1b = (const float*)d_in[10];
    const float* fc2w = (const float*)d_in[11];
    const float* fc2b = (const float*)d_in[12];
    const float* ln2g = (const float*)d_in[13];
    const float* ln2b = (const float*)d_in[14];
    const float* fc3w = (const float*)d_in[15];
    const float* fc3b = (const float*)d_in[16];
    const float* lnog = (const float*)d_in[17];
    const float* lnob = (const float*)d_in[18];

    // Fixed-tail workspace: P_relu(1MB) Tbuf(1MB) pad(512KB) z1p(4MB) tanh(8KB)
    const size_t FIXED = 1048576u + 1048576u + 524288u + 4194304u + 8192u;
    int ns = 16;
    if (ws_size < FIXED + 16u * 1048576u) {
        size_t avail = (ws_size > FIXED) ? (ws_size - FIXED) / 1048576u : 1u;
        ns = (int)avail;
        if (ns < 1) ns = 1;
        if (ns > 16) ns = 16;
    }

    char* ws = (char*)d_ws;
    float*    P_sum   = (float*)(ws + 0);                 // ns MB  [ns][2][32][4096]
    char*     rest    = ws + (size_t)ns * 1048576u;
    float*    P_relu  = (float*)(rest + 0);               // 1 MB   [2][32][4096]
    ushort_t* P_tbuf  = (ushort_t*)(rest + 1048576);      // 1 MB   ST,PT,OT,RT (bf16)
    float*    P_z1p   = (float*)(rest + 2621440);         // 4 MB   [64][32][512]
    float*    P_tanh  = (float*)(rest + 6815744);         // 8 KB   [32][64]

    float* out = (float*)d_out;

    if (ns < 16)  // atomic fallback needs zeroed partials
        hipMemsetAsync(P_sum, 0, (size_t)ns * 1048576u, stream);

    k_gemm_mfma<<<1024, 256, 0, stream>>>(stim, prev, Wheb, Wrec, P_sum, ns);
    k_reduce   <<<256,  256, 0, stream>>>(P_sum, stim, prev, P_relu, P_tbuf, ns);
    k_final_ln <<<32,   256, 0, stream>>>(P_relu, lnrg, lnrb, out);
    k_fc1      <<<64,   256, 0, stream>>>(out, fc1w, P_z1p);
    k_tail     <<<32,   256, 0, stream>>>(P_z1p, fc1b, ln1g, ln1b, fc2w, fc2b,
                                          ln2g, ln2b, fc3w, fc3b, lnog, lnob, P_tanh);
    k_update   <<<512,  512, 0, stream>>>(Wheb, Wrec, decay, P_tanh, P_tbuf, out);
}